// Round 9
// baseline (2075.792 us; speedup 1.0000x reference)
//
#include <hip/hip_runtime.h>
#include <hip/hip_bf16.h>
#include <float.h>

// Problem constants (OSG_C_29987461660961)
#define NTOK 2048
#define FDIM 1024
#define HDIM 512
#define EDIM 256
#define BATCH 2
#define KSEG 30
#define NP1 2049
static const size_t ST2 = (size_t)NP1 * NP1;   // Sp per-batch element count

// ---------------------------------------------------------------------------
// Shared NT GEMM: C[i][j] = sum_k A[i*lda+k]*B[j*ldb+k]  (+bias / relu / D-xform)
// ---------------------------------------------------------------------------
template<int MODE>
__global__ __launch_bounds__(256)
void gemm_nt(const float* __restrict__ A, int lda, size_t strideA,
             const float* __restrict__ Bm, int ldb, size_t strideB,
             const float* __restrict__ bias,
             float* __restrict__ C, int ldc, size_t strideC,
             int K, const float* __restrict__ dvec)
{
    __shared__ float As[32][68];
    __shared__ float Bs[32][68];
    const int z = blockIdx.z;
    const float* Ab = A + (size_t)z * strideA;
    const float* Bb = Bm + (size_t)z * strideB;
    float* Cb = C + (size_t)z * strideC;

    const int t = threadIdx.x;
    const int tx = t & 15, ty = t >> 4;
    const int lrow = t >> 3, lkv = t & 7;
    const int by = blockIdx.y, bx = blockIdx.x;

    float acc[4][4] = {};
    const int ktiles = K >> 5;
    for (int kt = 0; kt < ktiles; ++kt) {
#pragma unroll
        for (int h = 0; h < 2; ++h) {
            const int r = lrow + h * 32;
            const float4 av = *(const float4*)(Ab + (size_t)(by * 64 + r) * lda + kt * 32 + lkv * 4);
            As[lkv * 4 + 0][r] = av.x; As[lkv * 4 + 1][r] = av.y;
            As[lkv * 4 + 2][r] = av.z; As[lkv * 4 + 3][r] = av.w;
            const float4 bv = *(const float4*)(Bb + (size_t)(bx * 64 + r) * ldb + kt * 32 + lkv * 4);
            Bs[lkv * 4 + 0][r] = bv.x; Bs[lkv * 4 + 1][r] = bv.y;
            Bs[lkv * 4 + 2][r] = bv.z; Bs[lkv * 4 + 3][r] = bv.w;
        }
        __syncthreads();
#pragma unroll
        for (int kk = 0; kk < 32; ++kk) {
            const float4 a = *(const float4*)&As[kk][ty * 4];
            const float4 b = *(const float4*)&Bs[kk][tx * 4];
            const float ar[4] = {a.x, a.y, a.z, a.w};
            const float br[4] = {b.x, b.y, b.z, b.w};
#pragma unroll
            for (int i = 0; i < 4; ++i)
#pragma unroll
                for (int j = 0; j < 4; ++j)
                    acc[i][j] = fmaf(ar[i], br[j], acc[i][j]);
        }
        __syncthreads();
    }

    const int row0 = by * 64 + ty * 4;
    const int col0 = bx * 64 + tx * 4;
    if (MODE == 2) {
        float di[4], dj[4];
#pragma unroll
        for (int i = 0; i < 4; ++i) di[i] = dvec[z * NTOK + row0 + i];
#pragma unroll
        for (int j = 0; j < 4; ++j) dj[j] = dvec[z * NTOK + col0 + j];
#pragma unroll
        for (int i = 0; i < 4; ++i) {
            float4 v;
            float o[4];
#pragma unroll
            for (int j = 0; j < 4; ++j) {
                const float den = sqrtf(fmaxf(di[i] * dj[j], 1e-8f));
                o[j] = 0.5f * (1.0f - acc[i][j] / den);
            }
            v.x = o[0]; v.y = o[1]; v.z = o[2]; v.w = o[3];
            *(float4*)(Cb + (size_t)(row0 + i) * ldc + col0) = v;
        }
    } else {
#pragma unroll
        for (int i = 0; i < 4; ++i) {
            float o[4];
#pragma unroll
            for (int j = 0; j < 4; ++j) {
                float v = acc[i][j] + bias[col0 + j];
                if (MODE == 0) v = fmaxf(v, 0.0f);
                o[j] = v;
            }
            float4 v4; v4.x = o[0]; v4.y = o[1]; v4.z = o[2]; v4.w = o[3];
            *(float4*)(Cb + (size_t)(row0 + i) * ldc + col0) = v4;
        }
    }
}

__global__ __launch_bounds__(256)
void rownorm_kernel(const float* __restrict__ e, float* __restrict__ dvec)
{
    const int wid = (blockIdx.x * 256 + threadIdx.x) >> 6;
    const int lane = threadIdx.x & 63;
    if (wid >= BATCH * NTOK) return;
    const float4 v = *(const float4*)(e + (size_t)wid * EDIM + lane * 4);
    float s = v.x * v.x + v.y * v.y + v.z * v.z + v.w * v.w;
#pragma unroll
    for (int off = 32; off; off >>= 1) s += __shfl_xor(s, off);
    if (lane == 0) dvec[wid] = s;
}

// Row-wise inclusive scan of D (f32) into Sp rows 1..N (f64). Sp[r][0]=0.
__global__ __launch_bounds__(256)
void sat_row_kernel(const float* __restrict__ D, double* __restrict__ Sp)
{
    const int b = blockIdx.y;
    const int r = blockIdx.x + 1;
    const float* drow = D + (size_t)b * NTOK * NTOK + (size_t)(r - 1) * NTOK;
    double* sprow = Sp + (size_t)b * ST2 + (size_t)r * NP1;
    const int t = threadIdx.x, lane = t & 63, wv = t >> 6;
    __shared__ double wtot[4];
    double carry = 0.0;
    if (t == 0) sprow[0] = 0.0;
    for (int ch = 0; ch < NTOK / 256; ++ch) {
        double v = (double)drow[ch * 256 + t];
#pragma unroll
        for (int d = 1; d < 64; d <<= 1) {
            const double u = __shfl_up(v, (unsigned)d, 64);
            if (lane >= d) v += u;
        }
        if (lane == 63) wtot[wv] = v;
        __syncthreads();
        double pre = carry;
        for (int ww = 0; ww < wv; ++ww) pre += wtot[ww];
        const double tot = carry + wtot[0] + wtot[1] + wtot[2] + wtot[3];
        sprow[ch * 256 + t + 1] = v + pre;
        __syncthreads();
        carry = tot;
    }
}

// Column cumsum of Sp in 3 phases (strips of 256 rows).
__global__ void satc1(const double* __restrict__ Sp, double* __restrict__ aux)
{
    const int b = blockIdx.z, s = blockIdx.y;
    const int c = blockIdx.x * 256 + threadIdx.x;
    if (c > NTOK) return;
    const double* sp = Sp + (size_t)b * ST2;
    double tt = 0.0;
    const int r0 = s * 256 + 1;
    for (int r = r0; r < r0 + 256; ++r) tt += sp[(size_t)r * NP1 + c];
    aux[(size_t)(b * 8 + s) * NP1 + c] = tt;
}
__global__ void satc2(double* __restrict__ aux)
{
    const int b = blockIdx.y;
    const int c = blockIdx.x * 256 + threadIdx.x;
    if (c > NTOK) return;
    double run = 0.0;
    for (int s = 0; s < 8; ++s) {
        const size_t id = (size_t)(b * 8 + s) * NP1 + c;
        const double tt = aux[id]; aux[id] = run; run += tt;
    }
}
__global__ void satc3(double* __restrict__ Sp, const double* __restrict__ aux)
{
    const int b = blockIdx.z, s = blockIdx.y;
    const int c = blockIdx.x * 256 + threadIdx.x;
    if (c > NTOK) return;
    double* sp = Sp + (size_t)b * ST2;
    if (s == 0) sp[c] = 0.0;
    double run = aux[(size_t)(b * 8 + s) * NP1 + c];
    const int r0 = s * 256 + 1;
    for (int r = r0; r < r0 + 256; ++r) {
        const size_t id = (size_t)r * NP1 + c;
        run += sp[id];
        sp[id] = run;
    }
}

__global__ void diag_kernel(const double* __restrict__ Sp, double* __restrict__ dg)
{
    const int b = blockIdx.y;
    const int t = blockIdx.x * 256 + threadIdx.x;
    if (t <= NTOK) dg[b * NP1 + t] = Sp[(size_t)b * ST2 + (size_t)t * NP1 + t];
}

// Bsum[i][j] = diag[j+1] + diag[i] - 2*Sp[i][j+1] (f64 math -> f32), j >= i.
__global__ __launch_bounds__(256)
void bsum_kernel(const double* __restrict__ Sp, const double* __restrict__ dg,
                 float* __restrict__ Bsum, float* __restrict__ C0)
{
    const int b = blockIdx.y, i = blockIdx.x;
    const double* sprow = Sp + (size_t)b * ST2 + (size_t)i * NP1;
    const double* dgb = dg + (size_t)b * NP1;
    const double di = dgb[i];
    float* brow = Bsum + (size_t)b * NTOK * NTOK + (size_t)i * NTOK;
    for (int j = i + threadIdx.x; j < NTOK; j += 256) {
        const double v = dgb[j + 1] + di - 2.0 * sprow[j + 1];
        brow[j] = (float)v;
        if (j == NTOK - 1) C0[b * NTOK + i] = (float)v;
    }
}

// ---------------------------------------------------------------------------
// Sync v5: minimize coherence-point pressure.
//  - 64 blocks per batch (128 total participants, was 256).
//  - flags PACKED at 4B stride: 64 flags = 2 cachelines per batch.
//  - ONE wave polls (thread t<64 polls flag t), s_sleep(4) rate limit.
//  - C exchange: shifted plain cached reads + one acquire fence per step
//    (invalidates stale L2 copies of agent-scope-written C lines).
//  - publish = vmcnt drain + syncthreads + relaxed agent flag store.
// ---------------------------------------------------------------------------
#define DP_BX 64
#define DP_PAIRS 16

__device__ inline void cstore(float* p, float v)
{
    __hip_atomic_store(p, v, __ATOMIC_RELAXED, __HIP_MEMORY_SCOPE_AGENT);
}

__device__ inline void wait_flags(const int* flagsb, int need)
{
    if (threadIdx.x < DP_BX) {
        const int* f = flagsb + threadIdx.x;
        while (__hip_atomic_load(f, __ATOMIC_RELAXED, __HIP_MEMORY_SCOPE_AGENT) < need)
            __builtin_amdgcn_s_sleep(4);
    }
    __syncthreads();
    __builtin_amdgcn_fence(__ATOMIC_ACQUIRE, "agent");  // one inv; enables plain C reads
}

__device__ inline void publish(int* myflag, int val)
{
    asm volatile("s_waitcnt vmcnt(0)" ::: "memory");
    __syncthreads();
    if (threadIdx.x == 0)
        __hip_atomic_store(myflag, val, __ATOMIC_RELAXED, __HIP_MEMORY_SCOPE_AGENT);
}

// min pass: fill mv[] with Bsum+Cshift, return wave-reduced row min
template<int NC>
__device__ inline float minpass(const float* __restrict__ rb, const float* __restrict__ csv,
                                int coff, int V, int lane, float (&mv)[NC])
{
    float mn = FLT_MAX;
#pragma unroll
    for (int c = 0; c < NC; ++c) {
        const int idx = lane + c * 64;
        float v = FLT_MAX;
        if (idx < V) v = rb[idx] + csv[coff + idx];
        mv[c] = v;
        mn = fminf(mn, v);
    }
#pragma unroll
    for (int o = 32; o; o >>= 1) mn = fminf(mn, __shfl_xor(mn, o));
    return mn;
}

// exp pass: softmax weights from saved mv/mn, accumulate into LDS acc
template<int NC>
__device__ inline void exppass(float (&mv)[NC], float mn, int V, int lane,
                               float* __restrict__ accb)
{
    float s = 0.0f;
#pragma unroll
    for (int c = 0; c < NC; ++c) {
        const int idx = lane + c * 64;
        float w = 0.0f;
        if (idx < V) w = __expf(mn - mv[c]);
        mv[c] = w;
        s += w;
    }
#pragma unroll
    for (int o = 32; o; o >>= 1) s += __shfl_xor(s, o);
    const float inv = 1.0f / s;
#pragma unroll
    for (int c = 0; c < NC; ++c) {
        const int idx = lane + c * 64;
        if (idx < V) atomicAdd(&accb[idx], mv[c] * inv);
    }
}

// ---------------------------------------------------------------------------
// Fused DP: all 29 steps, Bsum upper-triangle parked in LDS.
// Grid (64, BATCH) x 256 threads, 16 row pairs (p, 2047-p) per block,
// 147.7KB LDS -> 1 block/CU, 128 blocks co-resident (cooperative launch).
// Each wave owns 4 pairs; all mv state held in registers across early-publish.
// ---------------------------------------------------------------------------
__global__ __launch_bounds__(256, 1)
void dp_fused_kernel(const float* __restrict__ Bsum,
                     float* __restrict__ Ca, float* __restrict__ Cb,
                     float* __restrict__ tsum, int* __restrict__ flags)
{
    __shared__ float rowbuf[DP_PAIRS][2052];
    __shared__ float cs[NTOK];
    __shared__ float acc[NTOK];
    const int b = blockIdx.y;
    const int t = threadIdx.x, lane = t & 63, wv = t >> 6;
    const float* Bb = Bsum + (size_t)b * NTOK * NTOK;
    const int pbase = blockIdx.x * DP_PAIRS;
    int* flagsb = flags + b * 64;          // 64 packed flags per batch (256B)
    int* myflag = flagsb + blockIdx.x;

    // coalesced whole-block load of each pair-row (row i0 cols p.., then row i1)
    for (int pr = 0; pr < DP_PAIRS; ++pr) {
        const int p = pbase + pr;
        const int L0 = NTOK - p;
        const float* r0 = Bb + (size_t)p * NTOK + p;
        const float* r1 = Bb + (size_t)(NTOK - 1 - p) * NTOK;
        for (int idx = t; idx <= NTOK; idx += 256)
            rowbuf[pr][idx] = (idx < L0) ? r0[idx] : r1[idx - 1];
    }
    for (int j = t; j < NTOK; j += 256) acc[j] = 0.0f;
    __syncthreads();
    // C0 (shifted): Csh[i-1] = Bsum[i][N-1]; index 0's row-0 value never read.
    if (t < DP_PAIRS) {
        const int p = pbase + t;
        if (p > 0) cstore(&Ca[b * NTOK + p - 1], rowbuf[t][NTOK - p - 1]);
        cstore(&Ca[b * NTOK + (NTOK - 2 - p)], rowbuf[t][NTOK]);
    }
    publish(myflag, 0);

    const float* Cr = Ca;
    float* Cn = Cb;

    for (int k = 1; k < KSEG; ++k) {
        wait_flags(flagsb, k - 1);         // all blocks of batch b published step k-1
        // cs[j] = C_{k-1}[j+1] : plain coalesced copy of the shifted vector
        {
            const float4* Cr4 = (const float4*)(Cr + b * NTOK);
            float4* cs4 = (float4*)cs;
#pragma unroll
            for (int r = 0; r < NTOK / 4 / 256; ++r)
                cs4[t + r * 256] = Cr4[t + r * 256];
        }
        __syncthreads();
        const int jmax = NTOK - k;
        float* Cnb = Cn + b * NTOK;

        // ---- min phase over this wave's 4 pairs (cross-block dependency) ----
        float mvA[4][32], mvB[4][16];
        float mnA[4], mnB[4];
        int VA[4], VB[4], P[4];
#pragma unroll
        for (int u = 0; u < 4; ++u) {
            const int p = pbase + wv * 4 + u;
            P[u] = p;
            const float* rb = rowbuf[wv * 4 + u];
            VA[u] = jmax - p;
            VB[u] = p + 1 - k;
            mnA[u] = minpass<32>(rb, cs, p, VA[u], lane, mvA[u]);
            mnB[u] = 0.0f;
            if (p >= k)
                mnB[u] = minpass<16>(rb + (NTOK - p), cs, NTOK - 1 - p, VB[u], lane, mvB[u]);
        }
        if (lane == 0) {
#pragma unroll
            for (int u = 0; u < 4; ++u) {
                if (P[u] > 0) cstore(&Cnb[P[u] - 1], mnA[u]);          // shifted store
                cstore(&Cnb[NTOK - 2 - P[u]], (P[u] >= k) ? mnB[u] : 0.0f);
            }
        }
        publish(myflag, k);                // early: exp pass needs no Cr/Cn access

        // ---- exp/accumulate phase (LDS only, hides under sync skew) ----
#pragma unroll
        for (int u = 0; u < 4; ++u) {
            exppass<32>(mvA[u], mnA[u], VA[u], lane, acc + P[u]);
            if (P[u] >= k) exppass<16>(mvB[u], mnB[u], VB[u], lane, acc + (NTOK - 1 - P[u]));
        }

        float* tmp = (float*)Cr; Cr = Cn; Cn = tmp;
    }
    // merge per-block acc into global tsum
    __syncthreads();
    float* ts = tsum + b * NTOK;
    for (int j = t; j < NTOK; j += 256) {
        const float v = acc[j];
        if (v != 0.0f) atomicAdd(&ts[j], v);
    }
}

// ---- fallback path (29 launches), kept in case cooperative launch fails ----
// (uses UNSHIFTED C vectors; CA holds unshifted C0 from bsum_kernel)
__global__ __launch_bounds__(256)
void dp_step_kernel(const float* __restrict__ Bsum, const float* __restrict__ Cprev,
                    float* __restrict__ Cnext, float* __restrict__ tsum, int kk)
{
    __shared__ float cs[NTOK];
    __shared__ float acc[NTOK];
    const int b = blockIdx.y;
    const int t = threadIdx.x, lane = t & 63, wv = t >> 6;
    const float* Cp = Cprev + b * NTOK;
    for (int j = t; j < NTOK; j += 256) {
        cs[j] = (j < NTOK - 1) ? Cp[j + 1] : 0.0f;
        acc[j] = 0.0f;
    }
    __syncthreads();
    const int jmax = NTOK - kk;
    const int w = blockIdx.x * 4 + wv;
    const float* Bb = Bsum + (size_t)b * NTOK * NTOK;
    float* Cn = Cnext + b * NTOK;
    const int rows[4] = { w, 1023 - w, 1024 + w, 2047 - w };
#pragma unroll
    for (int rr = 0; rr < 4; ++rr) {
        const int i = rows[rr];
        if (i >= jmax) { if (lane == 0) Cn[i] = 0.0f; continue; }
        const float* brow = Bb + (size_t)i * NTOK;
        const int j0 = i + lane;
        float mv[32];
        float mn = FLT_MAX;
#pragma unroll
        for (int c = 0; c < 32; ++c) {
            const int j = j0 + c * 64;
            float v = FLT_MAX;
            if (j < jmax) v = brow[j] + cs[j];
            mv[c] = v;
            mn = fminf(mn, v);
        }
#pragma unroll
        for (int off = 32; off; off >>= 1) mn = fminf(mn, __shfl_xor(mn, off));
        if (lane == 0) Cn[i] = mn;
        float s = 0.0f;
#pragma unroll
        for (int c = 0; c < 32; ++c) {
            const int j = j0 + c * 64;
            float p = 0.0f;
            if (j < jmax) p = __expf(mn - mv[c]);
            mv[c] = p;
            s += p;
        }
#pragma unroll
        for (int off = 32; off; off >>= 1) s += __shfl_xor(s, off);
        const float inv = 1.0f / s;
#pragma unroll
        for (int c = 0; c < 32; ++c) {
            const int j = j0 + c * 64;
            if (j < jmax) atomicAdd(&acc[j], mv[c] * inv);
        }
    }
    __syncthreads();
    float* ts = tsum + b * NTOK;
    for (int j = t; j < NTOK; j += 256) {
        const float v = acc[j];
        if (v != 0.0f) atomicAdd(&ts[j], v);
    }
}

__global__ void finalize_kernel(const float* __restrict__ tsum, float* __restrict__ out)
{
    const int b = blockIdx.y;
    const int j = blockIdx.x * 256 + threadIdx.x;
    if (j >= NTOK) return;
    float ts = tsum[b * NTOK + j];
    int steps = NTOK - 1 - j;
    if (steps > KSEG - 1) steps = KSEG - 1;
    float tc = (float)(j + 1) * (float)steps;
    if (j == NTOK - 1) { ts += (float)NTOK; tc += (float)NTOK; }
    out[b * NTOK + j] = ts / tc;
}

extern "C" void kernel_launch(void* const* d_in, const int* in_sizes, int n_in,
                              void* d_out, int out_size, void* d_ws, size_t ws_size,
                              hipStream_t stream)
{
    const float* x  = (const float*)d_in[0];
    const float* W0 = (const float*)d_in[1];
    const float* b0 = (const float*)d_in[2];
    const float* W1 = (const float*)d_in[3];
    const float* b1 = (const float*)d_in[4];
    float* out = (float*)d_out;

    char* ws = (char*)d_ws;
    size_t off = 0;
    auto alloc = [&](size_t bytes) -> void* {
        void* p = (void*)(ws + off);
        off += (bytes + 255) & ~(size_t)255;
        return p;
    };
    double* Sp   = (double*)alloc((size_t)BATCH * ST2 * sizeof(double));
    float*  Dm   = (float*) alloc((size_t)BATCH * NTOK * NTOK * sizeof(float));
    float*  h    = (float*) alloc((size_t)BATCH * NTOK * HDIM * sizeof(float));
    float*  e    = (float*) alloc((size_t)BATCH * NTOK * EDIM * sizeof(float));
    float*  dvec = (float*) alloc((size_t)BATCH * NTOK * sizeof(float));
    double* dg   = (double*)alloc((size_t)BATCH * NP1 * sizeof(double));
    double* aux  = (double*)alloc((size_t)BATCH * 8 * NP1 * sizeof(double));
    float*  CA   = (float*) alloc((size_t)BATCH * NTOK * sizeof(float));
    float*  CB   = (float*) alloc((size_t)BATCH * NTOK * sizeof(float));
    float*  tsum = (float*) alloc((size_t)BATCH * NTOK * sizeof(float));
    int*    flags= (int*)   alloc((size_t)BATCH * 64 * sizeof(int));
    (void)ws_size; (void)in_sizes; (void)n_in; (void)out_size;

    hipMemsetAsync(tsum, 0, (size_t)BATCH * NTOK * sizeof(float), stream);
    hipMemsetAsync(flags, 0xFF, (size_t)BATCH * 64 * sizeof(int), stream);  // -1

    gemm_nt<0><<<dim3(HDIM / 64, (BATCH * NTOK) / 64, 1), 256, 0, stream>>>(
        x, FDIM, 0, W0, FDIM, 0, b0, h, HDIM, 0, FDIM, nullptr);
    gemm_nt<1><<<dim3(EDIM / 64, (BATCH * NTOK) / 64, 1), 256, 0, stream>>>(
        h, HDIM, 0, W1, HDIM, 0, b1, e, EDIM, 0, HDIM, nullptr);
    rownorm_kernel<<<dim3((BATCH * NTOK) / 4), 256, 0, stream>>>(e, dvec);
    gemm_nt<2><<<dim3(NTOK / 64, NTOK / 64, BATCH), 256, 0, stream>>>(
        e, EDIM, (size_t)NTOK * EDIM, e, EDIM, (size_t)NTOK * EDIM, nullptr,
        Dm, NTOK, (size_t)NTOK * NTOK, EDIM, dvec);
    sat_row_kernel<<<dim3(NTOK, BATCH), 256, 0, stream>>>(Dm, Sp);
    satc1<<<dim3((NP1 + 255) / 256, 8, BATCH), 256, 0, stream>>>(Sp, aux);
    satc2<<<dim3((NP1 + 255) / 256, BATCH), 256, 0, stream>>>(aux);
    satc3<<<dim3((NP1 + 255) / 256, 8, BATCH), 256, 0, stream>>>(Sp, aux);
    diag_kernel<<<dim3((NP1 + 255) / 256, BATCH), 256, 0, stream>>>(Sp, dg);
    bsum_kernel<<<dim3(NTOK, BATCH), 256, 0, stream>>>(Sp, dg, Dm, CA);

    // Fused DP (cooperative launch for co-residency; packed-flag sync inside).
    void* args[] = { (void*)&Dm, (void*)&CA, (void*)&CB, (void*)&tsum, (void*)&flags };
    hipError_t err = hipLaunchCooperativeKernel((const void*)dp_fused_kernel,
                                                dim3(DP_BX, BATCH), dim3(256),
                                                args, 0, stream);
    if (err != hipSuccess) {
        // fallback: 29 separate step launches (CA already holds C0 from bsum_kernel)
        float* cp = CA; float* cn = CB;
        for (int kk = 1; kk < KSEG; ++kk) {
            dp_step_kernel<<<dim3(128, BATCH), 256, 0, stream>>>(Dm, cp, cn, tsum, kk);
            float* tmp = cp; cp = cn; cn = tmp;
        }
    }
    finalize_kernel<<<dim3(NTOK / 256, BATCH), 256, 0, stream>>>(tsum, out);
}

// Round 10
// 1261.415 us; speedup vs baseline: 1.6456x; 1.6456x over previous
//
#include <hip/hip_runtime.h>
#include <hip/hip_bf16.h>
#include <float.h>

// Problem constants (OSG_C_29987461660961)
#define NTOK 2048
#define FDIM 1024
#define HDIM 512
#define EDIM 256
#define BATCH 2
#define KSEG 30
#define NP1 2049
static const size_t ST2 = (size_t)NP1 * NP1;   // Sp per-batch element count

// ---------------------------------------------------------------------------
// Shared NT GEMM: C[i][j] = sum_k A[i*lda+k]*B[j*ldb+k]  (+bias / relu / D-xform)
// ---------------------------------------------------------------------------
template<int MODE>
__global__ __launch_bounds__(256)
void gemm_nt(const float* __restrict__ A, int lda, size_t strideA,
             const float* __restrict__ Bm, int ldb, size_t strideB,
             const float* __restrict__ bias,
             float* __restrict__ C, int ldc, size_t strideC,
             int K, const float* __restrict__ dvec)
{
    __shared__ float As[32][68];
    __shared__ float Bs[32][68];
    const int z = blockIdx.z;
    const float* Ab = A + (size_t)z * strideA;
    const float* Bb = Bm + (size_t)z * strideB;
    float* Cb = C + (size_t)z * strideC;

    const int t = threadIdx.x;
    const int tx = t & 15, ty = t >> 4;
    const int lrow = t >> 3, lkv = t & 7;
    const int by = blockIdx.y, bx = blockIdx.x;

    float acc[4][4] = {};
    const int ktiles = K >> 5;
    for (int kt = 0; kt < ktiles; ++kt) {
#pragma unroll
        for (int h = 0; h < 2; ++h) {
            const int r = lrow + h * 32;
            const float4 av = *(const float4*)(Ab + (size_t)(by * 64 + r) * lda + kt * 32 + lkv * 4);
            As[lkv * 4 + 0][r] = av.x; As[lkv * 4 + 1][r] = av.y;
            As[lkv * 4 + 2][r] = av.z; As[lkv * 4 + 3][r] = av.w;
            const float4 bv = *(const float4*)(Bb + (size_t)(bx * 64 + r) * ldb + kt * 32 + lkv * 4);
            Bs[lkv * 4 + 0][r] = bv.x; Bs[lkv * 4 + 1][r] = bv.y;
            Bs[lkv * 4 + 2][r] = bv.z; Bs[lkv * 4 + 3][r] = bv.w;
        }
        __syncthreads();
#pragma unroll
        for (int kk = 0; kk < 32; ++kk) {
            const float4 a = *(const float4*)&As[kk][ty * 4];
            const float4 b = *(const float4*)&Bs[kk][tx * 4];
            const float ar[4] = {a.x, a.y, a.z, a.w};
            const float br[4] = {b.x, b.y, b.z, b.w};
#pragma unroll
            for (int i = 0; i < 4; ++i)
#pragma unroll
                for (int j = 0; j < 4; ++j)
                    acc[i][j] = fmaf(ar[i], br[j], acc[i][j]);
        }
        __syncthreads();
    }

    const int row0 = by * 64 + ty * 4;
    const int col0 = bx * 64 + tx * 4;
    if (MODE == 2) {
        float di[4], dj[4];
#pragma unroll
        for (int i = 0; i < 4; ++i) di[i] = dvec[z * NTOK + row0 + i];
#pragma unroll
        for (int j = 0; j < 4; ++j) dj[j] = dvec[z * NTOK + col0 + j];
#pragma unroll
        for (int i = 0; i < 4; ++i) {
            float4 v;
            float o[4];
#pragma unroll
            for (int j = 0; j < 4; ++j) {
                const float den = sqrtf(fmaxf(di[i] * dj[j], 1e-8f));
                o[j] = 0.5f * (1.0f - acc[i][j] / den);
            }
            v.x = o[0]; v.y = o[1]; v.z = o[2]; v.w = o[3];
            *(float4*)(Cb + (size_t)(row0 + i) * ldc + col0) = v;
        }
    } else {
#pragma unroll
        for (int i = 0; i < 4; ++i) {
            float o[4];
#pragma unroll
            for (int j = 0; j < 4; ++j) {
                float v = acc[i][j] + bias[col0 + j];
                if (MODE == 0) v = fmaxf(v, 0.0f);
                o[j] = v;
            }
            float4 v4; v4.x = o[0]; v4.y = o[1]; v4.z = o[2]; v4.w = o[3];
            *(float4*)(Cb + (size_t)(row0 + i) * ldc + col0) = v4;
        }
    }
}

__global__ __launch_bounds__(256)
void rownorm_kernel(const float* __restrict__ e, float* __restrict__ dvec)
{
    const int wid = (blockIdx.x * 256 + threadIdx.x) >> 6;
    const int lane = threadIdx.x & 63;
    if (wid >= BATCH * NTOK) return;
    const float4 v = *(const float4*)(e + (size_t)wid * EDIM + lane * 4);
    float s = v.x * v.x + v.y * v.y + v.z * v.z + v.w * v.w;
#pragma unroll
    for (int off = 32; off; off >>= 1) s += __shfl_xor(s, off);
    if (lane == 0) dvec[wid] = s;
}

// Row-wise inclusive scan of D (f32) into Sp rows 1..N (f64). Sp[r][0]=0.
__global__ __launch_bounds__(256)
void sat_row_kernel(const float* __restrict__ D, double* __restrict__ Sp)
{
    const int b = blockIdx.y;
    const int r = blockIdx.x + 1;
    const float* drow = D + (size_t)b * NTOK * NTOK + (size_t)(r - 1) * NTOK;
    double* sprow = Sp + (size_t)b * ST2 + (size_t)r * NP1;
    const int t = threadIdx.x, lane = t & 63, wv = t >> 6;
    __shared__ double wtot[4];
    double carry = 0.0;
    if (t == 0) sprow[0] = 0.0;
    for (int ch = 0; ch < NTOK / 256; ++ch) {
        double v = (double)drow[ch * 256 + t];
#pragma unroll
        for (int d = 1; d < 64; d <<= 1) {
            const double u = __shfl_up(v, (unsigned)d, 64);
            if (lane >= d) v += u;
        }
        if (lane == 63) wtot[wv] = v;
        __syncthreads();
        double pre = carry;
        for (int ww = 0; ww < wv; ++ww) pre += wtot[ww];
        const double tot = carry + wtot[0] + wtot[1] + wtot[2] + wtot[3];
        sprow[ch * 256 + t + 1] = v + pre;
        __syncthreads();
        carry = tot;
    }
}

// Column cumsum of Sp in 3 phases (strips of 256 rows).
__global__ void satc1(const double* __restrict__ Sp, double* __restrict__ aux)
{
    const int b = blockIdx.z, s = blockIdx.y;
    const int c = blockIdx.x * 256 + threadIdx.x;
    if (c > NTOK) return;
    const double* sp = Sp + (size_t)b * ST2;
    double tt = 0.0;
    const int r0 = s * 256 + 1;
    for (int r = r0; r < r0 + 256; ++r) tt += sp[(size_t)r * NP1 + c];
    aux[(size_t)(b * 8 + s) * NP1 + c] = tt;
}
__global__ void satc2(double* __restrict__ aux)
{
    const int b = blockIdx.y;
    const int c = blockIdx.x * 256 + threadIdx.x;
    if (c > NTOK) return;
    double run = 0.0;
    for (int s = 0; s < 8; ++s) {
        const size_t id = (size_t)(b * 8 + s) * NP1 + c;
        const double tt = aux[id]; aux[id] = run; run += tt;
    }
}
__global__ void satc3(double* __restrict__ Sp, const double* __restrict__ aux)
{
    const int b = blockIdx.z, s = blockIdx.y;
    const int c = blockIdx.x * 256 + threadIdx.x;
    if (c > NTOK) return;
    double* sp = Sp + (size_t)b * ST2;
    if (s == 0) sp[c] = 0.0;
    double run = aux[(size_t)(b * 8 + s) * NP1 + c];
    const int r0 = s * 256 + 1;
    for (int r = r0; r < r0 + 256; ++r) {
        const size_t id = (size_t)r * NP1 + c;
        run += sp[id];
        sp[id] = run;
    }
}

__global__ void diag_kernel(const double* __restrict__ Sp, double* __restrict__ dg)
{
    const int b = blockIdx.y;
    const int t = blockIdx.x * 256 + threadIdx.x;
    if (t <= NTOK) dg[b * NP1 + t] = Sp[(size_t)b * ST2 + (size_t)t * NP1 + t];
}

// Bsum[i][j] = diag[j+1] + diag[i] - 2*Sp[i][j+1] (f64 math -> f32), j >= i.
__global__ __launch_bounds__(256)
void bsum_kernel(const double* __restrict__ Sp, const double* __restrict__ dg,
                 float* __restrict__ Bsum, float* __restrict__ C0)
{
    const int b = blockIdx.y, i = blockIdx.x;
    const double* sprow = Sp + (size_t)b * ST2 + (size_t)i * NP1;
    const double* dgb = dg + (size_t)b * NP1;
    const double di = dgb[i];
    float* brow = Bsum + (size_t)b * NTOK * NTOK + (size_t)i * NTOK;
    for (int j = i + threadIdx.x; j < NTOK; j += 256) {
        const double v = dgb[j + 1] + di - 2.0 * sprow[j + 1];
        brow[j] = (float)v;
        if (j == NTOK - 1) C0[b * NTOK + i] = (float)v;
    }
}

// ---------------------------------------------------------------------------
// Sync v6 = R8 structure + VALU-burn polling (anti-throttle).
// Theory: with waves parked in s_sleep/s_barrier the clock drops to its
// floor and everything (compute AND sync) runs ~10x slow. Keep VALUBusy
// high during waits so the clock stays up.
//  - publish = vmcnt drain + syncthreads + relaxed agent flag store
//  - wait    = ALL 256 threads poll (each a flag, x2 coverage) and burn
//              256 dependent FMAs between polls; then one acquire fence.
//  - C vectors PRE-SHIFTED, read as plain cached float4 (R8).
// ---------------------------------------------------------------------------
#define DP_BX 128
#define DP_PAIRS 8

__device__ inline void cstore(float* p, float v)
{
    __hip_atomic_store(p, v, __ATOMIC_RELAXED, __HIP_MEMORY_SCOPE_AGENT);
}

__device__ inline void wait_flags(const int* flagsb, int need)
{
    const int t = threadIdx.x;
    const int* f = flagsb + (t & (DP_BX - 1)) * 4;
    float x = 1.0f + (float)need * 1e-6f;
    while (__hip_atomic_load(f, __ATOMIC_RELAXED, __HIP_MEMORY_SCOPE_AGENT) < need) {
#pragma unroll
        for (int i = 0; i < 256; ++i)
            x = __builtin_fmaf(x, 1.0000001f, 1e-7f);   // dependent chain: pure VALU burn
        asm volatile("" :: "v"(x));                      // keep it alive
    }
    asm volatile("" :: "v"(x));
    __syncthreads();
    __builtin_amdgcn_fence(__ATOMIC_ACQUIRE, "agent");  // one inv; enables plain C reads
}

__device__ inline void publish(int* myflag, int val)
{
    asm volatile("s_waitcnt vmcnt(0)" ::: "memory");
    __syncthreads();
    if (threadIdx.x == 0)
        __hip_atomic_store(myflag, val, __ATOMIC_RELAXED, __HIP_MEMORY_SCOPE_AGENT);
}

// min pass: fill mv[] with Bsum+Cshift, return wave-reduced row min
template<int NC>
__device__ inline float minpass(const float* __restrict__ rb, const float* __restrict__ csv,
                                int coff, int V, int lane, float (&mv)[NC])
{
    float mn = FLT_MAX;
#pragma unroll
    for (int c = 0; c < NC; ++c) {
        const int idx = lane + c * 64;
        float v = FLT_MAX;
        if (idx < V) v = rb[idx] + csv[coff + idx];
        mv[c] = v;
        mn = fminf(mn, v);
    }
#pragma unroll
    for (int o = 32; o; o >>= 1) mn = fminf(mn, __shfl_xor(mn, o));
    return mn;
}

// exp pass: softmax weights from saved mv/mn, accumulate into LDS acc
template<int NC>
__device__ inline void exppass(float (&mv)[NC], float mn, int V, int lane,
                               float* __restrict__ accb)
{
    float s = 0.0f;
#pragma unroll
    for (int c = 0; c < NC; ++c) {
        const int idx = lane + c * 64;
        float w = 0.0f;
        if (idx < V) w = __expf(mn - mv[c]);
        mv[c] = w;
        s += w;
    }
#pragma unroll
    for (int o = 32; o; o >>= 1) s += __shfl_xor(s, o);
    const float inv = 1.0f / s;
#pragma unroll
    for (int c = 0; c < NC; ++c) {
        const int idx = lane + c * 64;
        if (idx < V) atomicAdd(&accb[idx], mv[c] * inv);
    }
}

// ---------------------------------------------------------------------------
// Fused DP: all 29 steps, Bsum upper-triangle parked in LDS.
// Grid (128, BATCH) x 256 threads, 8 row pairs (p, 2047-p) per block,
// 82KB LDS -> 1 block/CU, 256 blocks co-resident (cooperative launch).
// ---------------------------------------------------------------------------
__global__ __launch_bounds__(256)
void dp_fused_kernel(const float* __restrict__ Bsum,
                     float* __restrict__ Ca, float* __restrict__ Cb,
                     float* __restrict__ tsum, int* __restrict__ flags)
{
    __shared__ float rowbuf[DP_PAIRS][2052];
    __shared__ float cs[NTOK];
    __shared__ float acc[NTOK];
    const int b = blockIdx.y;
    const int t = threadIdx.x, lane = t & 63, wv = t >> 6;
    const float* Bb = Bsum + (size_t)b * NTOK * NTOK;
    const int pbase = blockIdx.x * DP_PAIRS;
    int* flagsb = flags + b * DP_BX * 4;
    int* myflag = flagsb + blockIdx.x * 4;

    // coalesced whole-block load of each pair-row (row i0 cols p.., then row i1)
    for (int pr = 0; pr < DP_PAIRS; ++pr) {
        const int p = pbase + pr;
        const int L0 = NTOK - p;
        const float* r0 = Bb + (size_t)p * NTOK + p;
        const float* r1 = Bb + (size_t)(NTOK - 1 - p) * NTOK;
        for (int idx = t; idx <= NTOK; idx += 256)
            rowbuf[pr][idx] = (idx < L0) ? r0[idx] : r1[idx - 1];
    }
    for (int j = t; j < NTOK; j += 256) acc[j] = 0.0f;
    __syncthreads();
    // C0 (shifted): Csh[i-1] = Bsum[i][N-1]; row 0's value is never read.
    for (int pr = t; pr < DP_PAIRS; pr += 256) {
        const int p = pbase + pr;
        if (p > 0) cstore(&Ca[b * NTOK + p - 1], rowbuf[pr][NTOK - p - 1]);
        cstore(&Ca[b * NTOK + (NTOK - 2 - p)], rowbuf[pr][NTOK]);
    }
    publish(myflag, 0);

    const float* Cr = Ca;
    float* Cn = Cb;
    const int p0 = pbase + wv * 2;
    const int p1 = p0 + 1;
    const float* rb0 = rowbuf[wv * 2];
    const float* rb1 = rowbuf[wv * 2 + 1];
    const int i1_0 = NTOK - 1 - p0, i1_1 = NTOK - 1 - p1;

    for (int k = 1; k < KSEG; ++k) {
        wait_flags(flagsb, k - 1);         // all blocks of batch b published step k-1
        // cs[j] = C_{k-1}[j+1] : plain coalesced copy of the shifted vector
        {
            const float4* Cr4 = (const float4*)(Cr + b * NTOK);
            float4* cs4 = (float4*)cs;
#pragma unroll
            for (int r = 0; r < NTOK / 4 / 256; ++r)
                cs4[t + r * 256] = Cr4[t + r * 256];
        }
        __syncthreads();
        const int jmax = NTOK - k;
        float* Cnb = Cn + b * NTOK;

        // ---- min phase (cross-block dependency) ----
        float mvA[32], mvB[16], mvC[32], mvD[16];
        const int VA = jmax - p0, VC = jmax - p1;
        const int VB = p0 + 1 - k, VD = p1 + 1 - k;
        const float mnA = minpass<32>(rb0, cs, p0, VA, lane, mvA);
        float mnB = 0.0f, mnD = 0.0f;
        if (p0 >= k) mnB = minpass<16>(rb0 + (NTOK - p0), cs, i1_0, VB, lane, mvB);
        const float mnC = minpass<32>(rb1, cs, p1, VC, lane, mvC);
        if (p1 >= k) mnD = minpass<16>(rb1 + (NTOK - p1), cs, i1_1, VD, lane, mvD);
        if (lane == 0) {
            if (p0 > 0) cstore(&Cnb[p0 - 1], mnA);     // shifted store
            cstore(&Cnb[i1_0 - 1], (p0 >= k) ? mnB : 0.0f);
            cstore(&Cnb[p1 - 1], mnC);
            cstore(&Cnb[i1_1 - 1], (p1 >= k) ? mnD : 0.0f);
        }
        publish(myflag, k);                // early: exp pass needs no Cr/Cn access

        // ---- exp/accumulate phase (LDS only, hides under sync skew) ----
        exppass<32>(mvA, mnA, VA, lane, acc + p0);
        if (p0 >= k) exppass<16>(mvB, mnB, VB, lane, acc + i1_0);
        exppass<32>(mvC, mnC, VC, lane, acc + p1);
        if (p1 >= k) exppass<16>(mvD, mnD, VD, lane, acc + i1_1);

        float* tmp = (float*)Cr; Cr = Cn; Cn = tmp;
    }
    // merge per-block acc into global tsum
    __syncthreads();
    float* ts = tsum + b * NTOK;
    for (int j = t; j < NTOK; j += 256) {
        const float v = acc[j];
        if (v != 0.0f) atomicAdd(&ts[j], v);
    }
}

// ---- fallback path (29 launches), kept in case cooperative launch fails ----
// (uses UNSHIFTED C vectors; CA holds unshifted C0 from bsum_kernel)
__global__ __launch_bounds__(256)
void dp_step_kernel(const float* __restrict__ Bsum, const float* __restrict__ Cprev,
                    float* __restrict__ Cnext, float* __restrict__ tsum, int kk)
{
    __shared__ float cs[NTOK];
    __shared__ float acc[NTOK];
    const int b = blockIdx.y;
    const int t = threadIdx.x, lane = t & 63, wv = t >> 6;
    const float* Cp = Cprev + b * NTOK;
    for (int j = t; j < NTOK; j += 256) {
        cs[j] = (j < NTOK - 1) ? Cp[j + 1] : 0.0f;
        acc[j] = 0.0f;
    }
    __syncthreads();
    const int jmax = NTOK - kk;
    const int w = blockIdx.x * 4 + wv;
    const float* Bb = Bsum + (size_t)b * NTOK * NTOK;
    float* Cn = Cnext + b * NTOK;
    const int rows[4] = { w, 1023 - w, 1024 + w, 2047 - w };
#pragma unroll
    for (int rr = 0; rr < 4; ++rr) {
        const int i = rows[rr];
        if (i >= jmax) { if (lane == 0) Cn[i] = 0.0f; continue; }
        const float* brow = Bb + (size_t)i * NTOK;
        const int j0 = i + lane;
        float mv[32];
        float mn = FLT_MAX;
#pragma unroll
        for (int c = 0; c < 32; ++c) {
            const int j = j0 + c * 64;
            float v = FLT_MAX;
            if (j < jmax) v = brow[j] + cs[j];
            mv[c] = v;
            mn = fminf(mn, v);
        }
#pragma unroll
        for (int off = 32; off; off >>= 1) mn = fminf(mn, __shfl_xor(mn, off));
        if (lane == 0) Cn[i] = mn;
        float s = 0.0f;
#pragma unroll
        for (int c = 0; c < 32; ++c) {
            const int j = j0 + c * 64;
            float p = 0.0f;
            if (j < jmax) p = __expf(mn - mv[c]);
            mv[c] = p;
            s += p;
        }
#pragma unroll
        for (int off = 32; off; off >>= 1) s += __shfl_xor(s, off);
        const float inv = 1.0f / s;
#pragma unroll
        for (int c = 0; c < 32; ++c) {
            const int j = j0 + c * 64;
            if (j < jmax) atomicAdd(&acc[j], mv[c] * inv);
        }
    }
    __syncthreads();
    float* ts = tsum + b * NTOK;
    for (int j = t; j < NTOK; j += 256) {
        const float v = acc[j];
        if (v != 0.0f) atomicAdd(&ts[j], v);
    }
}

__global__ void finalize_kernel(const float* __restrict__ tsum, float* __restrict__ out)
{
    const int b = blockIdx.y;
    const int j = blockIdx.x * 256 + threadIdx.x;
    if (j >= NTOK) return;
    float ts = tsum[b * NTOK + j];
    int steps = NTOK - 1 - j;
    if (steps > KSEG - 1) steps = KSEG - 1;
    float tc = (float)(j + 1) * (float)steps;
    if (j == NTOK - 1) { ts += (float)NTOK; tc += (float)NTOK; }
    out[b * NTOK + j] = ts / tc;
}

extern "C" void kernel_launch(void* const* d_in, const int* in_sizes, int n_in,
                              void* d_out, int out_size, void* d_ws, size_t ws_size,
                              hipStream_t stream)
{
    const float* x  = (const float*)d_in[0];
    const float* W0 = (const float*)d_in[1];
    const float* b0 = (const float*)d_in[2];
    const float* W1 = (const float*)d_in[3];
    const float* b1 = (const float*)d_in[4];
    float* out = (float*)d_out;

    char* ws = (char*)d_ws;
    size_t off = 0;
    auto alloc = [&](size_t bytes) -> void* {
        void* p = (void*)(ws + off);
        off += (bytes + 255) & ~(size_t)255;
        return p;
    };
    double* Sp   = (double*)alloc((size_t)BATCH * ST2 * sizeof(double));
    float*  Dm   = (float*) alloc((size_t)BATCH * NTOK * NTOK * sizeof(float));
    float*  h    = (float*) alloc((size_t)BATCH * NTOK * HDIM * sizeof(float));
    float*  e    = (float*) alloc((size_t)BATCH * NTOK * EDIM * sizeof(float));
    float*  dvec = (float*) alloc((size_t)BATCH * NTOK * sizeof(float));
    double* dg   = (double*)alloc((size_t)BATCH * NP1 * sizeof(double));
    double* aux  = (double*)alloc((size_t)BATCH * 8 * NP1 * sizeof(double));
    float*  CA   = (float*) alloc((size_t)BATCH * NTOK * sizeof(float));
    float*  CB   = (float*) alloc((size_t)BATCH * NTOK * sizeof(float));
    float*  tsum = (float*) alloc((size_t)BATCH * NTOK * sizeof(float));
    int*    flags= (int*)   alloc((size_t)BATCH * DP_BX * 4 * sizeof(int));
    (void)ws_size; (void)in_sizes; (void)n_in; (void)out_size;

    hipMemsetAsync(tsum, 0, (size_t)BATCH * NTOK * sizeof(float), stream);
    hipMemsetAsync(flags, 0xFF, (size_t)BATCH * DP_BX * 4 * sizeof(int), stream);  // -1

    gemm_nt<0><<<dim3(HDIM / 64, (BATCH * NTOK) / 64, 1), 256, 0, stream>>>(
        x, FDIM, 0, W0, FDIM, 0, b0, h, HDIM, 0, FDIM, nullptr);
    gemm_nt<1><<<dim3(EDIM / 64, (BATCH * NTOK) / 64, 1), 256, 0, stream>>>(
        h, HDIM, 0, W1, HDIM, 0, b1, e, EDIM, 0, HDIM, nullptr);
    rownorm_kernel<<<dim3((BATCH * NTOK) / 4), 256, 0, stream>>>(e, dvec);
    gemm_nt<2><<<dim3(NTOK / 64, NTOK / 64, BATCH), 256, 0, stream>>>(
        e, EDIM, (size_t)NTOK * EDIM, e, EDIM, (size_t)NTOK * EDIM, nullptr,
        Dm, NTOK, (size_t)NTOK * NTOK, EDIM, dvec);
    sat_row_kernel<<<dim3(NTOK, BATCH), 256, 0, stream>>>(Dm, Sp);
    satc1<<<dim3((NP1 + 255) / 256, 8, BATCH), 256, 0, stream>>>(Sp, aux);
    satc2<<<dim3((NP1 + 255) / 256, BATCH), 256, 0, stream>>>(aux);
    satc3<<<dim3((NP1 + 255) / 256, 8, BATCH), 256, 0, stream>>>(Sp, aux);
    diag_kernel<<<dim3((NP1 + 255) / 256, BATCH), 256, 0, stream>>>(Sp, dg);
    bsum_kernel<<<dim3(NTOK, BATCH), 256, 0, stream>>>(Sp, dg, Dm, CA);

    // Fused DP (cooperative launch for co-residency; burn-poll flag sync inside).
    void* args[] = { (void*)&Dm, (void*)&CA, (void*)&CB, (void*)&tsum, (void*)&flags };
    hipError_t err = hipLaunchCooperativeKernel((const void*)dp_fused_kernel,
                                                dim3(DP_BX, BATCH), dim3(256),
                                                args, 0, stream);
    if (err != hipSuccess) {
        // fallback: 29 separate step launches (CA already holds C0 from bsum_kernel)
        float* cp = CA; float* cn = CB;
        for (int kk = 1; kk < KSEG; ++kk) {
            dp_step_kernel<<<dim3(128, BATCH), 256, 0, stream>>>(Dm, cp, cn, tsum, kk);
            float* tmp = cp; cp = cn; cn = tmp;
        }
    }
    finalize_kernel<<<dim3(NTOK / 256, BATCH), 256, 0, stream>>>(tsum, out);
}

// Round 11
// 982.820 us; speedup vs baseline: 2.1121x; 1.2835x over previous
//
#include <hip/hip_runtime.h>
#include <hip/hip_bf16.h>
#include <float.h>

// Problem constants (OSG_C_29987461660961)
#define NTOK 2048
#define FDIM 1024
#define HDIM 512
#define EDIM 256
#define BATCH 2
#define KSEG 30
#define NP1 2049
static const size_t ST2 = (size_t)NP1 * NP1;   // Sp per-batch element count

// ---------------------------------------------------------------------------
// Shared NT GEMM: C[i][j] = sum_k A[i*lda+k]*B[j*ldb+k]  (+bias / relu / D-xform)
// ---------------------------------------------------------------------------
template<int MODE>
__global__ __launch_bounds__(256)
void gemm_nt(const float* __restrict__ A, int lda, size_t strideA,
             const float* __restrict__ Bm, int ldb, size_t strideB,
             const float* __restrict__ bias,
             float* __restrict__ C, int ldc, size_t strideC,
             int K, const float* __restrict__ dvec)
{
    __shared__ float As[32][68];
    __shared__ float Bs[32][68];
    const int z = blockIdx.z;
    const float* Ab = A + (size_t)z * strideA;
    const float* Bb = Bm + (size_t)z * strideB;
    float* Cb = C + (size_t)z * strideC;

    const int t = threadIdx.x;
    const int tx = t & 15, ty = t >> 4;
    const int lrow = t >> 3, lkv = t & 7;
    const int by = blockIdx.y, bx = blockIdx.x;

    float acc[4][4] = {};
    const int ktiles = K >> 5;
    for (int kt = 0; kt < ktiles; ++kt) {
#pragma unroll
        for (int h = 0; h < 2; ++h) {
            const int r = lrow + h * 32;
            const float4 av = *(const float4*)(Ab + (size_t)(by * 64 + r) * lda + kt * 32 + lkv * 4);
            As[lkv * 4 + 0][r] = av.x; As[lkv * 4 + 1][r] = av.y;
            As[lkv * 4 + 2][r] = av.z; As[lkv * 4 + 3][r] = av.w;
            const float4 bv = *(const float4*)(Bb + (size_t)(bx * 64 + r) * ldb + kt * 32 + lkv * 4);
            Bs[lkv * 4 + 0][r] = bv.x; Bs[lkv * 4 + 1][r] = bv.y;
            Bs[lkv * 4 + 2][r] = bv.z; Bs[lkv * 4 + 3][r] = bv.w;
        }
        __syncthreads();
#pragma unroll
        for (int kk = 0; kk < 32; ++kk) {
            const float4 a = *(const float4*)&As[kk][ty * 4];
            const float4 b = *(const float4*)&Bs[kk][tx * 4];
            const float ar[4] = {a.x, a.y, a.z, a.w};
            const float br[4] = {b.x, b.y, b.z, b.w};
#pragma unroll
            for (int i = 0; i < 4; ++i)
#pragma unroll
                for (int j = 0; j < 4; ++j)
                    acc[i][j] = fmaf(ar[i], br[j], acc[i][j]);
        }
        __syncthreads();
    }

    const int row0 = by * 64 + ty * 4;
    const int col0 = bx * 64 + tx * 4;
    if (MODE == 2) {
        float di[4], dj[4];
#pragma unroll
        for (int i = 0; i < 4; ++i) di[i] = dvec[z * NTOK + row0 + i];
#pragma unroll
        for (int j = 0; j < 4; ++j) dj[j] = dvec[z * NTOK + col0 + j];
#pragma unroll
        for (int i = 0; i < 4; ++i) {
            float4 v;
            float o[4];
#pragma unroll
            for (int j = 0; j < 4; ++j) {
                const float den = sqrtf(fmaxf(di[i] * dj[j], 1e-8f));
                o[j] = 0.5f * (1.0f - acc[i][j] / den);
            }
            v.x = o[0]; v.y = o[1]; v.z = o[2]; v.w = o[3];
            *(float4*)(Cb + (size_t)(row0 + i) * ldc + col0) = v;
        }
    } else {
#pragma unroll
        for (int i = 0; i < 4; ++i) {
            float o[4];
#pragma unroll
            for (int j = 0; j < 4; ++j) {
                float v = acc[i][j] + bias[col0 + j];
                if (MODE == 0) v = fmaxf(v, 0.0f);
                o[j] = v;
            }
            float4 v4; v4.x = o[0]; v4.y = o[1]; v4.z = o[2]; v4.w = o[3];
            *(float4*)(Cb + (size_t)(row0 + i) * ldc + col0) = v4;
        }
    }
}

__global__ __launch_bounds__(256)
void rownorm_kernel(const float* __restrict__ e, float* __restrict__ dvec)
{
    const int wid = (blockIdx.x * 256 + threadIdx.x) >> 6;
    const int lane = threadIdx.x & 63;
    if (wid >= BATCH * NTOK) return;
    const float4 v = *(const float4*)(e + (size_t)wid * EDIM + lane * 4);
    float s = v.x * v.x + v.y * v.y + v.z * v.z + v.w * v.w;
#pragma unroll
    for (int off = 32; off; off >>= 1) s += __shfl_xor(s, off);
    if (lane == 0) dvec[wid] = s;
}

// Row-wise inclusive scan of D (f32) into Sp rows 1..N (f64). Sp[r][0]=0.
__global__ __launch_bounds__(256)
void sat_row_kernel(const float* __restrict__ D, double* __restrict__ Sp)
{
    const int b = blockIdx.y;
    const int r = blockIdx.x + 1;
    const float* drow = D + (size_t)b * NTOK * NTOK + (size_t)(r - 1) * NTOK;
    double* sprow = Sp + (size_t)b * ST2 + (size_t)r * NP1;
    const int t = threadIdx.x, lane = t & 63, wv = t >> 6;
    __shared__ double wtot[4];
    double carry = 0.0;
    if (t == 0) sprow[0] = 0.0;
    for (int ch = 0; ch < NTOK / 256; ++ch) {
        double v = (double)drow[ch * 256 + t];
#pragma unroll
        for (int d = 1; d < 64; d <<= 1) {
            const double u = __shfl_up(v, (unsigned)d, 64);
            if (lane >= d) v += u;
        }
        if (lane == 63) wtot[wv] = v;
        __syncthreads();
        double pre = carry;
        for (int ww = 0; ww < wv; ++ww) pre += wtot[ww];
        const double tot = carry + wtot[0] + wtot[1] + wtot[2] + wtot[3];
        sprow[ch * 256 + t + 1] = v + pre;
        __syncthreads();
        carry = tot;
    }
}

// Column cumsum of Sp in 3 phases (strips of 256 rows).
__global__ void satc1(const double* __restrict__ Sp, double* __restrict__ aux)
{
    const int b = blockIdx.z, s = blockIdx.y;
    const int c = blockIdx.x * 256 + threadIdx.x;
    if (c > NTOK) return;
    const double* sp = Sp + (size_t)b * ST2;
    double tt = 0.0;
    const int r0 = s * 256 + 1;
    for (int r = r0; r < r0 + 256; ++r) tt += sp[(size_t)r * NP1 + c];
    aux[(size_t)(b * 8 + s) * NP1 + c] = tt;
}
__global__ void satc2(double* __restrict__ aux)
{
    const int b = blockIdx.y;
    const int c = blockIdx.x * 256 + threadIdx.x;
    if (c > NTOK) return;
    double run = 0.0;
    for (int s = 0; s < 8; ++s) {
        const size_t id = (size_t)(b * 8 + s) * NP1 + c;
        const double tt = aux[id]; aux[id] = run; run += tt;
    }
}
__global__ void satc3(double* __restrict__ Sp, const double* __restrict__ aux)
{
    const int b = blockIdx.z, s = blockIdx.y;
    const int c = blockIdx.x * 256 + threadIdx.x;
    if (c > NTOK) return;
    double* sp = Sp + (size_t)b * ST2;
    if (s == 0) sp[c] = 0.0;
    double run = aux[(size_t)(b * 8 + s) * NP1 + c];
    const int r0 = s * 256 + 1;
    for (int r = r0; r < r0 + 256; ++r) {
        const size_t id = (size_t)r * NP1 + c;
        run += sp[id];
        sp[id] = run;
    }
}

__global__ void diag_kernel(const double* __restrict__ Sp, double* __restrict__ dg)
{
    const int b = blockIdx.y;
    const int t = blockIdx.x * 256 + threadIdx.x;
    if (t <= NTOK) dg[b * NP1 + t] = Sp[(size_t)b * ST2 + (size_t)t * NP1 + t];
}

// Bsum[i][j] = diag[j+1] + diag[i] - 2*Sp[i][j+1] (f64 math -> f32), j >= i.
__global__ __launch_bounds__(256)
void bsum_kernel(const double* __restrict__ Sp, const double* __restrict__ dg,
                 float* __restrict__ Bsum, float* __restrict__ C0)
{
    const int b = blockIdx.y, i = blockIdx.x;
    const double* sprow = Sp + (size_t)b * ST2 + (size_t)i * NP1;
    const double* dgb = dg + (size_t)b * NP1;
    const double di = dgb[i];
    float* brow = Bsum + (size_t)b * NTOK * NTOK + (size_t)i * NTOK;
    for (int j = i + threadIdx.x; j < NTOK; j += 256) {
        const double v = dgb[j + 1] + di - 2.0 * sprow[j + 1];
        brow[j] = (float)v;
        if (j == NTOK - 1) C0[b * NTOK + i] = (float)v;
    }
}

// ---------------------------------------------------------------------------
// DP v7: ALL-REGISTER step body (zero LDS traffic in the k loop).
// At 1 block/CU, 4 waves/CU = 1 wave/SIMD -> up to 512 VGPRs/wave available.
// Per wave: 2 pairs (p, 2047-p). Registers: rb (Bsum rows, 96), mv (96),
// acc (softmax column accums, fixed per-lane addresses, 96).
// Step: fence -> coalesced global loads of shifted C fused into add -> min ->
// shuffle reduce -> 4 agent-scope C stores -> publish -> exp+fma in regs
// (sync shadow). LDS (8KB) used once at the end for the acc merge.
// Sync = R8 proven: packed-ish flags (16B stride), relaxed poll, one acquire
// fence per step, vmcnt-drain publish.
// ---------------------------------------------------------------------------
#define DP_BX 128
#define DP_PAIRS 8
#define RBBIG 3.0e37f

__device__ inline void cstore(float* p, float v)
{
    __hip_atomic_store(p, v, __ATOMIC_RELAXED, __HIP_MEMORY_SCOPE_AGENT);
}

__device__ inline void wait_flags(const int* flagsb, int need)
{
    if (threadIdx.x < DP_BX) {
        const int* f = flagsb + threadIdx.x * 4;
        while (__hip_atomic_load(f, __ATOMIC_RELAXED, __HIP_MEMORY_SCOPE_AGENT) < need)
            __builtin_amdgcn_s_sleep(1);
    }
    __syncthreads();
    __builtin_amdgcn_fence(__ATOMIC_ACQUIRE, "agent");  // one inv; enables plain C reads
}

__device__ inline void publish(int* myflag, int val)
{
    asm volatile("s_waitcnt vmcnt(0)" ::: "memory");
    __syncthreads();
    if (threadIdx.x == 0)
        __hip_atomic_store(myflag, val, __ATOMIC_RELAXED, __HIP_MEMORY_SCOPE_AGENT);
}

// load Bsum row segment into registers (coalesced; OOB -> RBBIG)
template<int NC>
__device__ inline void load_rb(const float* __restrict__ brow, int colbase, int lane,
                               float (&rb)[NC])
{
#pragma unroll
    for (int c = 0; c < NC; ++c) {
        const int col = colbase + lane + c * 64;
        rb[c] = (col < NTOK) ? brow[col] : RBBIG;
    }
}

// pass1: v = rb + Csh[base+idx] (plain global, predicated), row min
template<int NC>
__device__ inline float pass1(const float (&rb)[NC], const float* __restrict__ Csh,
                              int base, int V, int lane, float (&mv)[NC])
{
    float mn = FLT_MAX;
#pragma unroll
    for (int c = 0; c < NC; ++c) {
        const int idx = lane + c * 64;
        float v = FLT_MAX;
        if (idx < V) v = rb[c] + Csh[base + idx];
        mv[c] = v;
        mn = fminf(mn, v);
    }
#pragma unroll
    for (int o = 32; o; o >>= 1) mn = fminf(mn, __shfl_xor(mn, o));
    return mn;
}

// pass2: softmax weights from mv/mn, accumulate into register acc
template<int NC>
__device__ inline void pass2(float (&mv)[NC], float mn, float (&ac)[NC])
{
    float s = 0.0f;
#pragma unroll
    for (int c = 0; c < NC; ++c) {
        const float w = __expf(mn - mv[c]);   // exp(-huge)=0 for invalid slots
        mv[c] = w;
        s += w;
    }
#pragma unroll
    for (int o = 32; o; o >>= 1) s += __shfl_xor(s, o);
    const float inv = 1.0f / s;
#pragma unroll
    for (int c = 0; c < NC; ++c) ac[c] = __builtin_fmaf(mv[c], inv, ac[c]);
}

template<int NC>
__device__ inline void merge_acc(const float (&ac)[NC], int base, int lane,
                                 float* __restrict__ acc_lds)
{
#pragma unroll
    for (int c = 0; c < NC; ++c) {
        const int col = base + lane + c * 64;
        if (col < NTOK && ac[c] != 0.0f) atomicAdd(&acc_lds[col], ac[c]);
    }
}

__global__ __launch_bounds__(256, 1)
void dp_fused_kernel(const float* __restrict__ Bsum,
                     float* __restrict__ Ca, float* __restrict__ Cb,
                     float* __restrict__ tsum, int* __restrict__ flags)
{
    __shared__ float acc_lds[NTOK];
    const int b = blockIdx.y;
    const int t = threadIdx.x, lane = t & 63, wv = t >> 6;
    const float* Bb = Bsum + (size_t)b * NTOK * NTOK;
    const int pbase = blockIdx.x * DP_PAIRS;
    int* flagsb = flags + b * DP_BX * 4;
    int* myflag = flagsb + blockIdx.x * 4;

    const int p0 = pbase + wv * 2, p1 = p0 + 1;
    const int i1_0 = NTOK - 1 - p0, i1_1 = NTOK - 1 - p1;

    // ---- one-time register load of Bsum pair rows (coalesced) ----
    float rbA0[32], rbB0[16], rbA1[32], rbB1[16];
    load_rb<32>(Bb + (size_t)p0 * NTOK, p0, lane, rbA0);
    load_rb<16>(Bb + (size_t)i1_0 * NTOK, i1_0, lane, rbB0);
    load_rb<32>(Bb + (size_t)p1 * NTOK, p1, lane, rbA1);
    load_rb<16>(Bb + (size_t)i1_1 * NTOK, i1_1, lane, rbB1);

    float acA0[32] = {}, acB0[16] = {}, acA1[32] = {}, acB1[16] = {};

    for (int j = t; j < NTOK; j += 256) acc_lds[j] = 0.0f;

    // ---- C0 (shifted): Csh[i-1] = Bsum[i][N-1] ----
    if (t < DP_PAIRS) {
        const int p = pbase + t, i1 = NTOK - 1 - p;
        if (p > 0) cstore(&Ca[b * NTOK + p - 1], Bb[(size_t)p * NTOK + NTOK - 1]);
        cstore(&Ca[b * NTOK + i1 - 1], Bb[(size_t)i1 * NTOK + NTOK - 1]);
    }
    publish(myflag, 0);

    const float* Cr = Ca;
    float* Cn = Cb;

    for (int k = 1; k < KSEG; ++k) {
        wait_flags(flagsb, k - 1);
        const float* Csh = Cr + b * NTOK;
        float* Cnb = Cn + b * NTOK;
        const int jmax = NTOK - k;

        // ---- min phase (reads Csh via plain cached loads) ----
        float mvA0[32], mvB0[16], mvA1[32], mvB1[16];
        const int VA0 = jmax - p0, VA1 = jmax - p1;
        const int VB0 = p0 + 1 - k, VB1 = p1 + 1 - k;
        const float mnA0 = pass1<32>(rbA0, Csh, p0, VA0, lane, mvA0);
        float mnB0 = 0.0f, mnB1 = 0.0f;
        if (p0 >= k) mnB0 = pass1<16>(rbB0, Csh, i1_0, VB0, lane, mvB0);
        const float mnA1 = pass1<32>(rbA1, Csh, p1, VA1, lane, mvA1);
        if (p1 >= k) mnB1 = pass1<16>(rbB1, Csh, i1_1, VB1, lane, mvB1);
        if (lane == 0) {
            if (p0 > 0) cstore(&Cnb[p0 - 1], mnA0);
            cstore(&Cnb[i1_0 - 1], (p0 >= k) ? mnB0 : 0.0f);
            cstore(&Cnb[p1 - 1], mnA1);
            cstore(&Cnb[i1_1 - 1], (p1 >= k) ? mnB1 : 0.0f);
        }
        publish(myflag, k);   // early: exp phase is register-only

        // ---- exp/accumulate phase (pure registers, sync shadow) ----
        pass2<32>(mvA0, mnA0, acA0);
        if (p0 >= k) pass2<16>(mvB0, mnB0, acB0);
        pass2<32>(mvA1, mnA1, acA1);
        if (p1 >= k) pass2<16>(mvB1, mnB1, acB1);

        float* tmp = (float*)Cr; Cr = Cn; Cn = tmp;
    }

    // ---- one-time merge: regs -> LDS -> global tsum ----
    __syncthreads();
    merge_acc<32>(acA0, p0, lane, acc_lds);
    merge_acc<16>(acB0, i1_0, lane, acc_lds);
    merge_acc<32>(acA1, p1, lane, acc_lds);
    merge_acc<16>(acB1, i1_1, lane, acc_lds);
    __syncthreads();
    float* ts = tsum + b * NTOK;
    for (int j = t; j < NTOK; j += 256) {
        const float v = acc_lds[j];
        if (v != 0.0f) atomicAdd(&ts[j], v);
    }
}

// ---- fallback path (29 launches), kept in case cooperative launch fails ----
// (uses UNSHIFTED C vectors; CA holds unshifted C0 from bsum_kernel)
__global__ __launch_bounds__(256)
void dp_step_kernel(const float* __restrict__ Bsum, const float* __restrict__ Cprev,
                    float* __restrict__ Cnext, float* __restrict__ tsum, int kk)
{
    __shared__ float cs[NTOK];
    __shared__ float acc[NTOK];
    const int b = blockIdx.y;
    const int t = threadIdx.x, lane = t & 63, wv = t >> 6;
    const float* Cp = Cprev + b * NTOK;
    for (int j = t; j < NTOK; j += 256) {
        cs[j] = (j < NTOK - 1) ? Cp[j + 1] : 0.0f;
        acc[j] = 0.0f;
    }
    __syncthreads();
    const int jmax = NTOK - kk;
    const int w = blockIdx.x * 4 + wv;
    const float* Bb = Bsum + (size_t)b * NTOK * NTOK;
    float* Cn = Cnext + b * NTOK;
    const int rows[4] = { w, 1023 - w, 1024 + w, 2047 - w };
#pragma unroll
    for (int rr = 0; rr < 4; ++rr) {
        const int i = rows[rr];
        if (i >= jmax) { if (lane == 0) Cn[i] = 0.0f; continue; }
        const float* brow = Bb + (size_t)i * NTOK;
        const int j0 = i + lane;
        float mv[32];
        float mn = FLT_MAX;
#pragma unroll
        for (int c = 0; c < 32; ++c) {
            const int j = j0 + c * 64;
            float v = FLT_MAX;
            if (j < jmax) v = brow[j] + cs[j];
            mv[c] = v;
            mn = fminf(mn, v);
        }
#pragma unroll
        for (int off = 32; off; off >>= 1) mn = fminf(mn, __shfl_xor(mn, off));
        if (lane == 0) Cn[i] = mn;
        float s = 0.0f;
#pragma unroll
        for (int c = 0; c < 32; ++c) {
            const int j = j0 + c * 64;
            float p = 0.0f;
            if (j < jmax) p = __expf(mn - mv[c]);
            mv[c] = p;
            s += p;
        }
#pragma unroll
        for (int off = 32; off; off >>= 1) s += __shfl_xor(s, off);
        const float inv = 1.0f / s;
#pragma unroll
        for (int c = 0; c < 32; ++c) {
            const int j = j0 + c * 64;
            if (j < jmax) atomicAdd(&acc[j], mv[c] * inv);
        }
    }
    __syncthreads();
    float* ts = tsum + b * NTOK;
    for (int j = t; j < NTOK; j += 256) {
        const float v = acc[j];
        if (v != 0.0f) atomicAdd(&ts[j], v);
    }
}

__global__ void finalize_kernel(const float* __restrict__ tsum, float* __restrict__ out)
{
    const int b = blockIdx.y;
    const int j = blockIdx.x * 256 + threadIdx.x;
    if (j >= NTOK) return;
    float ts = tsum[b * NTOK + j];
    int steps = NTOK - 1 - j;
    if (steps > KSEG - 1) steps = KSEG - 1;
    float tc = (float)(j + 1) * (float)steps;
    if (j == NTOK - 1) { ts += (float)NTOK; tc += (float)NTOK; }
    out[b * NTOK + j] = ts / tc;
}

extern "C" void kernel_launch(void* const* d_in, const int* in_sizes, int n_in,
                              void* d_out, int out_size, void* d_ws, size_t ws_size,
                              hipStream_t stream)
{
    const float* x  = (const float*)d_in[0];
    const float* W0 = (const float*)d_in[1];
    const float* b0 = (const float*)d_in[2];
    const float* W1 = (const float*)d_in[3];
    const float* b1 = (const float*)d_in[4];
    float* out = (float*)d_out;

    char* ws = (char*)d_ws;
    size_t off = 0;
    auto alloc = [&](size_t bytes) -> void* {
        void* p = (void*)(ws + off);
        off += (bytes + 255) & ~(size_t)255;
        return p;
    };
    double* Sp   = (double*)alloc((size_t)BATCH * ST2 * sizeof(double));
    float*  Dm   = (float*) alloc((size_t)BATCH * NTOK * NTOK * sizeof(float));
    float*  h    = (float*) alloc((size_t)BATCH * NTOK * HDIM * sizeof(float));
    float*  e    = (float*) alloc((size_t)BATCH * NTOK * EDIM * sizeof(float));
    float*  dvec = (float*) alloc((size_t)BATCH * NTOK * sizeof(float));
    double* dg   = (double*)alloc((size_t)BATCH * NP1 * sizeof(double));
    double* aux  = (double*)alloc((size_t)BATCH * 8 * NP1 * sizeof(double));
    float*  CA   = (float*) alloc((size_t)BATCH * NTOK * sizeof(float));
    float*  CB   = (float*) alloc((size_t)BATCH * NTOK * sizeof(float));
    float*  tsum = (float*) alloc((size_t)BATCH * NTOK * sizeof(float));
    int*    flags= (int*)   alloc((size_t)BATCH * DP_BX * 4 * sizeof(int));
    (void)ws_size; (void)in_sizes; (void)n_in; (void)out_size;

    hipMemsetAsync(tsum, 0, (size_t)BATCH * NTOK * sizeof(float), stream);
    hipMemsetAsync(flags, 0xFF, (size_t)BATCH * DP_BX * 4 * sizeof(int), stream);  // -1

    gemm_nt<0><<<dim3(HDIM / 64, (BATCH * NTOK) / 64, 1), 256, 0, stream>>>(
        x, FDIM, 0, W0, FDIM, 0, b0, h, HDIM, 0, FDIM, nullptr);
    gemm_nt<1><<<dim3(EDIM / 64, (BATCH * NTOK) / 64, 1), 256, 0, stream>>>(
        h, HDIM, 0, W1, HDIM, 0, b1, e, EDIM, 0, HDIM, nullptr);
    rownorm_kernel<<<dim3((BATCH * NTOK) / 4), 256, 0, stream>>>(e, dvec);
    gemm_nt<2><<<dim3(NTOK / 64, NTOK / 64, BATCH), 256, 0, stream>>>(
        e, EDIM, (size_t)NTOK * EDIM, e, EDIM, (size_t)NTOK * EDIM, nullptr,
        Dm, NTOK, (size_t)NTOK * NTOK, EDIM, dvec);
    sat_row_kernel<<<dim3(NTOK, BATCH), 256, 0, stream>>>(Dm, Sp);
    satc1<<<dim3((NP1 + 255) / 256, 8, BATCH), 256, 0, stream>>>(Sp, aux);
    satc2<<<dim3((NP1 + 255) / 256, BATCH), 256, 0, stream>>>(aux);
    satc3<<<dim3((NP1 + 255) / 256, 8, BATCH), 256, 0, stream>>>(Sp, aux);
    diag_kernel<<<dim3((NP1 + 255) / 256, BATCH), 256, 0, stream>>>(Sp, dg);
    bsum_kernel<<<dim3(NTOK, BATCH), 256, 0, stream>>>(Sp, dg, Dm, CA);

    // Fused DP (cooperative launch for co-residency; all-register step body).
    void* args[] = { (void*)&Dm, (void*)&CA, (void*)&CB, (void*)&tsum, (void*)&flags };
    hipError_t err = hipLaunchCooperativeKernel((const void*)dp_fused_kernel,
                                                dim3(DP_BX, BATCH), dim3(256),
                                                args, 0, stream);
    if (err != hipSuccess) {
        // fallback: 29 separate step launches (CA already holds C0 from bsum_kernel)
        float* cp = CA; float* cn = CB;
        for (int kk = 1; kk < KSEG; ++kk) {
            dp_step_kernel<<<dim3(128, BATCH), 256, 0, stream>>>(Dm, cp, cn, tsum, kk);
            float* tmp = cp; cp = cn; cn = tmp;
        }
    }
    finalize_kernel<<<dim3(NTOK / 256, BATCH), 256, 0, stream>>>(tsum, out);
}

// Round 12
// 836.998 us; speedup vs baseline: 2.4800x; 1.1742x over previous
//
#include <hip/hip_runtime.h>
#include <hip/hip_bf16.h>
#include <float.h>

// Problem constants (OSG_C_29987461660961)
#define NTOK 2048
#define FDIM 1024
#define HDIM 512
#define EDIM 256
#define BATCH 2
#define KSEG 30
#define NP1 2049
static const size_t ST2 = (size_t)NP1 * NP1;   // Sp per-batch element count

// ---------------------------------------------------------------------------
// Shared NT GEMM: C[i][j] = sum_k A[i*lda+k]*B[j*ldb+k]  (+bias / relu / D-xform)
// ---------------------------------------------------------------------------
template<int MODE>
__global__ __launch_bounds__(256)
void gemm_nt(const float* __restrict__ A, int lda, size_t strideA,
             const float* __restrict__ Bm, int ldb, size_t strideB,
             const float* __restrict__ bias,
             float* __restrict__ C, int ldc, size_t strideC,
             int K, const float* __restrict__ dvec)
{
    __shared__ float As[32][68];
    __shared__ float Bs[32][68];
    const int z = blockIdx.z;
    const float* Ab = A + (size_t)z * strideA;
    const float* Bb = Bm + (size_t)z * strideB;
    float* Cb = C + (size_t)z * strideC;

    const int t = threadIdx.x;
    const int tx = t & 15, ty = t >> 4;
    const int lrow = t >> 3, lkv = t & 7;
    const int by = blockIdx.y, bx = blockIdx.x;

    float acc[4][4] = {};
    const int ktiles = K >> 5;
    for (int kt = 0; kt < ktiles; ++kt) {
#pragma unroll
        for (int h = 0; h < 2; ++h) {
            const int r = lrow + h * 32;
            const float4 av = *(const float4*)(Ab + (size_t)(by * 64 + r) * lda + kt * 32 + lkv * 4);
            As[lkv * 4 + 0][r] = av.x; As[lkv * 4 + 1][r] = av.y;
            As[lkv * 4 + 2][r] = av.z; As[lkv * 4 + 3][r] = av.w;
            const float4 bv = *(const float4*)(Bb + (size_t)(bx * 64 + r) * ldb + kt * 32 + lkv * 4);
            Bs[lkv * 4 + 0][r] = bv.x; Bs[lkv * 4 + 1][r] = bv.y;
            Bs[lkv * 4 + 2][r] = bv.z; Bs[lkv * 4 + 3][r] = bv.w;
        }
        __syncthreads();
#pragma unroll
        for (int kk = 0; kk < 32; ++kk) {
            const float4 a = *(const float4*)&As[kk][ty * 4];
            const float4 b = *(const float4*)&Bs[kk][tx * 4];
            const float ar[4] = {a.x, a.y, a.z, a.w};
            const float br[4] = {b.x, b.y, b.z, b.w};
#pragma unroll
            for (int i = 0; i < 4; ++i)
#pragma unroll
                for (int j = 0; j < 4; ++j)
                    acc[i][j] = fmaf(ar[i], br[j], acc[i][j]);
        }
        __syncthreads();
    }

    const int row0 = by * 64 + ty * 4;
    const int col0 = bx * 64 + tx * 4;
    if (MODE == 2) {
        float di[4], dj[4];
#pragma unroll
        for (int i = 0; i < 4; ++i) di[i] = dvec[z * NTOK + row0 + i];
#pragma unroll
        for (int j = 0; j < 4; ++j) dj[j] = dvec[z * NTOK + col0 + j];
#pragma unroll
        for (int i = 0; i < 4; ++i) {
            float4 v;
            float o[4];
#pragma unroll
            for (int j = 0; j < 4; ++j) {
                const float den = sqrtf(fmaxf(di[i] * dj[j], 1e-8f));
                o[j] = 0.5f * (1.0f - acc[i][j] / den);
            }
            v.x = o[0]; v.y = o[1]; v.z = o[2]; v.w = o[3];
            *(float4*)(Cb + (size_t)(row0 + i) * ldc + col0) = v;
        }
    } else {
#pragma unroll
        for (int i = 0; i < 4; ++i) {
            float o[4];
#pragma unroll
            for (int j = 0; j < 4; ++j) {
                float v = acc[i][j] + bias[col0 + j];
                if (MODE == 0) v = fmaxf(v, 0.0f);
                o[j] = v;
            }
            float4 v4; v4.x = o[0]; v4.y = o[1]; v4.z = o[2]; v4.w = o[3];
            *(float4*)(Cb + (size_t)(row0 + i) * ldc + col0) = v4;
        }
    }
}

__global__ __launch_bounds__(256)
void rownorm_kernel(const float* __restrict__ e, float* __restrict__ dvec)
{
    const int wid = (blockIdx.x * 256 + threadIdx.x) >> 6;
    const int lane = threadIdx.x & 63;
    if (wid >= BATCH * NTOK) return;
    const float4 v = *(const float4*)(e + (size_t)wid * EDIM + lane * 4);
    float s = v.x * v.x + v.y * v.y + v.z * v.z + v.w * v.w;
#pragma unroll
    for (int off = 32; off; off >>= 1) s += __shfl_xor(s, off);
    if (lane == 0) dvec[wid] = s;
}

// Row-wise inclusive scan of D (f32) into Sp rows 1..N (f64). Sp[r][0]=0.
__global__ __launch_bounds__(256)
void sat_row_kernel(const float* __restrict__ D, double* __restrict__ Sp)
{
    const int b = blockIdx.y;
    const int r = blockIdx.x + 1;
    const float* drow = D + (size_t)b * NTOK * NTOK + (size_t)(r - 1) * NTOK;
    double* sprow = Sp + (size_t)b * ST2 + (size_t)r * NP1;
    const int t = threadIdx.x, lane = t & 63, wv = t >> 6;
    __shared__ double wtot[4];
    double carry = 0.0;
    if (t == 0) sprow[0] = 0.0;
    for (int ch = 0; ch < NTOK / 256; ++ch) {
        double v = (double)drow[ch * 256 + t];
#pragma unroll
        for (int d = 1; d < 64; d <<= 1) {
            const double u = __shfl_up(v, (unsigned)d, 64);
            if (lane >= d) v += u;
        }
        if (lane == 63) wtot[wv] = v;
        __syncthreads();
        double pre = carry;
        for (int ww = 0; ww < wv; ++ww) pre += wtot[ww];
        const double tot = carry + wtot[0] + wtot[1] + wtot[2] + wtot[3];
        sprow[ch * 256 + t + 1] = v + pre;
        __syncthreads();
        carry = tot;
    }
}

// Column cumsum of Sp in 3 phases (strips of 256 rows).
__global__ void satc1(const double* __restrict__ Sp, double* __restrict__ aux)
{
    const int b = blockIdx.z, s = blockIdx.y;
    const int c = blockIdx.x * 256 + threadIdx.x;
    if (c > NTOK) return;
    const double* sp = Sp + (size_t)b * ST2;
    double tt = 0.0;
    const int r0 = s * 256 + 1;
    for (int r = r0; r < r0 + 256; ++r) tt += sp[(size_t)r * NP1 + c];
    aux[(size_t)(b * 8 + s) * NP1 + c] = tt;
}
__global__ void satc2(double* __restrict__ aux)
{
    const int b = blockIdx.y;
    const int c = blockIdx.x * 256 + threadIdx.x;
    if (c > NTOK) return;
    double run = 0.0;
    for (int s = 0; s < 8; ++s) {
        const size_t id = (size_t)(b * 8 + s) * NP1 + c;
        const double tt = aux[id]; aux[id] = run; run += tt;
    }
}
__global__ void satc3(double* __restrict__ Sp, const double* __restrict__ aux)
{
    const int b = blockIdx.z, s = blockIdx.y;
    const int c = blockIdx.x * 256 + threadIdx.x;
    if (c > NTOK) return;
    double* sp = Sp + (size_t)b * ST2;
    if (s == 0) sp[c] = 0.0;
    double run = aux[(size_t)(b * 8 + s) * NP1 + c];
    const int r0 = s * 256 + 1;
    for (int r = r0; r < r0 + 256; ++r) {
        const size_t id = (size_t)r * NP1 + c;
        run += sp[id];
        sp[id] = run;
    }
}

__global__ void diag_kernel(const double* __restrict__ Sp, double* __restrict__ dg)
{
    const int b = blockIdx.y;
    const int t = blockIdx.x * 256 + threadIdx.x;
    if (t <= NTOK) dg[b * NP1 + t] = Sp[(size_t)b * ST2 + (size_t)t * NP1 + t];
}

// Bsum[i][j] = diag[j+1] + diag[i] - 2*Sp[i][j+1] (f64 math -> f32), j >= i.
__global__ __launch_bounds__(256)
void bsum_kernel(const double* __restrict__ Sp, const double* __restrict__ dg,
                 float* __restrict__ Bsum, float* __restrict__ C0)
{
    const int b = blockIdx.y, i = blockIdx.x;
    const double* sprow = Sp + (size_t)b * ST2 + (size_t)i * NP1;
    const double* dgb = dg + (size_t)b * NP1;
    const double di = dgb[i];
    float* brow = Bsum + (size_t)b * NTOK * NTOK + (size_t)i * NTOK;
    for (int j = i + threadIdx.x; j < NTOK; j += 256) {
        const double v = dgb[j + 1] + di - 2.0 * sprow[j + 1];
        brow[j] = (float)v;
        if (j == NTOK - 1) C0[b * NTOK + i] = (float)v;
    }
}

// ---------------------------------------------------------------------------
// DP v8: register rb/acc + LDS cs snapshot, NO mv arrays (pass2 recomputes
// rb+cs from LDS). Peak live regs ~235 < 256 -> no scratch spill (R11's
// killer: 288 live -> spills -> 14MB/step HBM write traffic).
// Safety of the pass2 re-read: cs is a block-private LDS snapshot; its next
// overwrite is ordered behind wait_flags' __syncthreads.
// Sync = R8 proven: flag array, relaxed poll, one acquire fence per step,
// vmcnt-drain publish, early publish (pass2 in sync shadow).
// ---------------------------------------------------------------------------
#define DP_BX 128
#define DP_PAIRS 8
#define RBBIG 3.0e37f

__device__ inline void cstore(float* p, float v)
{
    __hip_atomic_store(p, v, __ATOMIC_RELAXED, __HIP_MEMORY_SCOPE_AGENT);
}

__device__ inline void wait_flags(const int* flagsb, int need)
{
    if (threadIdx.x < DP_BX) {
        const int* f = flagsb + threadIdx.x * 4;
        while (__hip_atomic_load(f, __ATOMIC_RELAXED, __HIP_MEMORY_SCOPE_AGENT) < need)
            __builtin_amdgcn_s_sleep(1);
    }
    __syncthreads();
    __builtin_amdgcn_fence(__ATOMIC_ACQUIRE, "agent");  // one inv; enables plain C reads
}

__device__ inline void publish(int* myflag, int val)
{
    asm volatile("s_waitcnt vmcnt(0)" ::: "memory");
    __syncthreads();
    if (threadIdx.x == 0)
        __hip_atomic_store(myflag, val, __ATOMIC_RELAXED, __HIP_MEMORY_SCOPE_AGENT);
}

// load Bsum row segment into registers (coalesced; OOB -> RBBIG)
template<int NC>
__device__ inline void load_rb(const float* __restrict__ brow, int colbase, int lane,
                               float (&rb)[NC])
{
#pragma unroll
    for (int c = 0; c < NC; ++c) {
        const int col = colbase + lane + c * 64;
        rb[c] = (col < NTOK) ? brow[col] : RBBIG;
    }
}

// pass1: row min of rb + cs (LDS), no value stash
template<int NC>
__device__ inline float pass1(const float (&rb)[NC], const float* __restrict__ cs,
                              int coff, int V, int lane)
{
    float mn = FLT_MAX;
#pragma unroll
    for (int c = 0; c < NC; ++c) {
        const int idx = lane + c * 64;
        if (idx < V) mn = fminf(mn, rb[c] + cs[coff + idx]);
    }
#pragma unroll
    for (int o = 32; o; o >>= 1) mn = fminf(mn, __shfl_xor(mn, o));
    return mn;
}

// pass2: recompute values from rb + cs (LDS), softmax, accumulate into reg acc
template<int NC>
__device__ inline void pass2(const float (&rb)[NC], const float* __restrict__ cs,
                             int coff, int V, float mn, int lane, float (&ac)[NC])
{
    float w[NC];
    float s = 0.0f;
#pragma unroll
    for (int c = 0; c < NC; ++c) {
        const int idx = lane + c * 64;
        float x = 0.0f;
        if (idx < V) x = __expf(mn - (rb[c] + cs[coff + idx]));
        w[c] = x;
        s += x;
    }
#pragma unroll
    for (int o = 32; o; o >>= 1) s += __shfl_xor(s, o);
    const float inv = 1.0f / s;
#pragma unroll
    for (int c = 0; c < NC; ++c) ac[c] = __builtin_fmaf(w[c], inv, ac[c]);
}

template<int NC>
__device__ inline void merge_acc(const float (&ac)[NC], int base, int lane,
                                 float* __restrict__ acc_lds)
{
#pragma unroll
    for (int c = 0; c < NC; ++c) {
        const int col = base + lane + c * 64;
        if (col < NTOK && ac[c] != 0.0f) atomicAdd(&acc_lds[col], ac[c]);
    }
}

__global__ __launch_bounds__(256, 1)
void dp_fused_kernel(const float* __restrict__ Bsum,
                     float* __restrict__ Ca, float* __restrict__ Cb,
                     float* __restrict__ tsum, int* __restrict__ flags)
{
    __shared__ float cs[NTOK];
    __shared__ float acc_lds[NTOK];
    const int b = blockIdx.y;
    const int t = threadIdx.x, lane = t & 63, wv = t >> 6;
    const float* Bb = Bsum + (size_t)b * NTOK * NTOK;
    const int pbase = blockIdx.x * DP_PAIRS;
    int* flagsb = flags + b * DP_BX * 4;
    int* myflag = flagsb + blockIdx.x * 4;

    const int p0 = pbase + wv * 2, p1 = p0 + 1;
    const int i1_0 = NTOK - 1 - p0, i1_1 = NTOK - 1 - p1;

    // ---- one-time register load of Bsum pair rows (coalesced) ----
    float rbA0[32], rbB0[16], rbA1[32], rbB1[16];
    load_rb<32>(Bb + (size_t)p0 * NTOK, p0, lane, rbA0);
    load_rb<16>(Bb + (size_t)i1_0 * NTOK, i1_0, lane, rbB0);
    load_rb<32>(Bb + (size_t)p1 * NTOK, p1, lane, rbA1);
    load_rb<16>(Bb + (size_t)i1_1 * NTOK, i1_1, lane, rbB1);

    float acA0[32] = {}, acB0[16] = {}, acA1[32] = {}, acB1[16] = {};

    for (int j = t; j < NTOK; j += 256) acc_lds[j] = 0.0f;

    // ---- C0 (shifted): Csh[i-1] = Bsum[i][N-1] ----
    if (t < DP_PAIRS) {
        const int p = pbase + t, i1 = NTOK - 1 - p;
        if (p > 0) cstore(&Ca[b * NTOK + p - 1], Bb[(size_t)p * NTOK + NTOK - 1]);
        cstore(&Ca[b * NTOK + i1 - 1], Bb[(size_t)i1 * NTOK + NTOK - 1]);
    }
    publish(myflag, 0);

    const float* Cr = Ca;
    float* Cn = Cb;

    for (int k = 1; k < KSEG; ++k) {
        wait_flags(flagsb, k - 1);
        // cs snapshot: plain coalesced copy of the shifted C vector
        {
            const float4* Cr4 = (const float4*)(Cr + b * NTOK);
            float4* cs4 = (float4*)cs;
#pragma unroll
            for (int r = 0; r < NTOK / 4 / 256; ++r)
                cs4[t + r * 256] = Cr4[t + r * 256];
        }
        __syncthreads();
        float* Cnb = Cn + b * NTOK;
        const int jmax = NTOK - k;

        // ---- min phase ----
        const int VA0 = jmax - p0, VA1 = jmax - p1;
        const int VB0 = p0 + 1 - k, VB1 = p1 + 1 - k;
        const float mnA0 = pass1<32>(rbA0, cs, p0, VA0, lane);
        float mnB0 = 0.0f, mnB1 = 0.0f;
        if (p0 >= k) mnB0 = pass1<16>(rbB0, cs, i1_0, VB0, lane);
        const float mnA1 = pass1<32>(rbA1, cs, p1, VA1, lane);
        if (p1 >= k) mnB1 = pass1<16>(rbB1, cs, i1_1, VB1, lane);
        if (lane == 0) {
            if (p0 > 0) cstore(&Cnb[p0 - 1], mnA0);
            cstore(&Cnb[i1_0 - 1], (p0 >= k) ? mnB0 : 0.0f);
            cstore(&Cnb[p1 - 1], mnA1);
            cstore(&Cnb[i1_1 - 1], (p1 >= k) ? mnB1 : 0.0f);
        }
        publish(myflag, k);   // early: pass2 uses only LDS cs + registers

        // ---- exp/accumulate phase (sync shadow; cs stable until next fill) ----
        pass2<32>(rbA0, cs, p0, VA0, mnA0, lane, acA0);
        if (p0 >= k) pass2<16>(rbB0, cs, i1_0, VB0, mnB0, lane, acB0);
        pass2<32>(rbA1, cs, p1, VA1, mnA1, lane, acA1);
        if (p1 >= k) pass2<16>(rbB1, cs, i1_1, VB1, mnB1, lane, acB1);

        float* tmp = (float*)Cr; Cr = Cn; Cn = tmp;
    }

    // ---- one-time merge: regs -> LDS -> global tsum ----
    __syncthreads();
    merge_acc<32>(acA0, p0, lane, acc_lds);
    merge_acc<16>(acB0, i1_0, lane, acc_lds);
    merge_acc<32>(acA1, p1, lane, acc_lds);
    merge_acc<16>(acB1, i1_1, lane, acc_lds);
    __syncthreads();
    float* ts = tsum + b * NTOK;
    for (int j = t; j < NTOK; j += 256) {
        const float v = acc_lds[j];
        if (v != 0.0f) atomicAdd(&ts[j], v);
    }
}

// ---- fallback path (29 launches), kept in case cooperative launch fails ----
// (uses UNSHIFTED C vectors; CA holds unshifted C0 from bsum_kernel)
__global__ __launch_bounds__(256)
void dp_step_kernel(const float* __restrict__ Bsum, const float* __restrict__ Cprev,
                    float* __restrict__ Cnext, float* __restrict__ tsum, int kk)
{
    __shared__ float cs[NTOK];
    __shared__ float acc[NTOK];
    const int b = blockIdx.y;
    const int t = threadIdx.x, lane = t & 63, wv = t >> 6;
    const float* Cp = Cprev + b * NTOK;
    for (int j = t; j < NTOK; j += 256) {
        cs[j] = (j < NTOK - 1) ? Cp[j + 1] : 0.0f;
        acc[j] = 0.0f;
    }
    __syncthreads();
    const int jmax = NTOK - kk;
    const int w = blockIdx.x * 4 + wv;
    const float* Bb = Bsum + (size_t)b * NTOK * NTOK;
    float* Cn = Cnext + b * NTOK;
    const int rows[4] = { w, 1023 - w, 1024 + w, 2047 - w };
#pragma unroll
    for (int rr = 0; rr < 4; ++rr) {
        const int i = rows[rr];
        if (i >= jmax) { if (lane == 0) Cn[i] = 0.0f; continue; }
        const float* brow = Bb + (size_t)i * NTOK;
        const int j0 = i + lane;
        float mv[32];
        float mn = FLT_MAX;
#pragma unroll
        for (int c = 0; c < 32; ++c) {
            const int j = j0 + c * 64;
            float v = FLT_MAX;
            if (j < jmax) v = brow[j] + cs[j];
            mv[c] = v;
            mn = fminf(mn, v);
        }
#pragma unroll
        for (int off = 32; off; off >>= 1) mn = fminf(mn, __shfl_xor(mn, off));
        if (lane == 0) Cn[i] = mn;
        float s = 0.0f;
#pragma unroll
        for (int c = 0; c < 32; ++c) {
            const int j = j0 + c * 64;
            float p = 0.0f;
            if (j < jmax) p = __expf(mn - mv[c]);
            mv[c] = p;
            s += p;
        }
#pragma unroll
        for (int off = 32; off; off >>= 1) s += __shfl_xor(s, off);
        const float inv = 1.0f / s;
#pragma unroll
        for (int c = 0; c < 32; ++c) {
            const int j = j0 + c * 64;
            if (j < jmax) atomicAdd(&acc[j], mv[c] * inv);
        }
    }
    __syncthreads();
    float* ts = tsum + b * NTOK;
    for (int j = t; j < NTOK; j += 256) {
        const float v = acc[j];
        if (v != 0.0f) atomicAdd(&ts[j], v);
    }
}

__global__ void finalize_kernel(const float* __restrict__ tsum, float* __restrict__ out)
{
    const int b = blockIdx.y;
    const int j = blockIdx.x * 256 + threadIdx.x;
    if (j >= NTOK) return;
    float ts = tsum[b * NTOK + j];
    int steps = NTOK - 1 - j;
    if (steps > KSEG - 1) steps = KSEG - 1;
    float tc = (float)(j + 1) * (float)steps;
    if (j == NTOK - 1) { ts += (float)NTOK; tc += (float)NTOK; }
    out[b * NTOK + j] = ts / tc;
}

extern "C" void kernel_launch(void* const* d_in, const int* in_sizes, int n_in,
                              void* d_out, int out_size, void* d_ws, size_t ws_size,
                              hipStream_t stream)
{
    const float* x  = (const float*)d_in[0];
    const float* W0 = (const float*)d_in[1];
    const float* b0 = (const float*)d_in[2];
    const float* W1 = (const float*)d_in[3];
    const float* b1 = (const float*)d_in[4];
    float* out = (float*)d_out;

    char* ws = (char*)d_ws;
    size_t off = 0;
    auto alloc = [&](size_t bytes) -> void* {
        void* p = (void*)(ws + off);
        off += (bytes + 255) & ~(size_t)255;
        return p;
    };
    double* Sp   = (double*)alloc((size_t)BATCH * ST2 * sizeof(double));
    float*  Dm   = (float*) alloc((size_t)BATCH * NTOK * NTOK * sizeof(float));
    float*  h    = (float*) alloc((size_t)BATCH * NTOK * HDIM * sizeof(float));
    float*  e    = (float*) alloc((size_t)BATCH * NTOK * EDIM * sizeof(float));
    float*  dvec = (float*) alloc((size_t)BATCH * NTOK * sizeof(float));
    double* dg   = (double*)alloc((size_t)BATCH * NP1 * sizeof(double));
    double* aux  = (double*)alloc((size_t)BATCH * 8 * NP1 * sizeof(double));
    float*  CA   = (float*) alloc((size_t)BATCH * NTOK * sizeof(float));
    float*  CB   = (float*) alloc((size_t)BATCH * NTOK * sizeof(float));
    float*  tsum = (float*) alloc((size_t)BATCH * NTOK * sizeof(float));
    int*    flags= (int*)   alloc((size_t)BATCH * DP_BX * 4 * sizeof(int));
    (void)ws_size; (void)in_sizes; (void)n_in; (void)out_size;

    hipMemsetAsync(tsum, 0, (size_t)BATCH * NTOK * sizeof(float), stream);
    hipMemsetAsync(flags, 0xFF, (size_t)BATCH * DP_BX * 4 * sizeof(int), stream);  // -1

    gemm_nt<0><<<dim3(HDIM / 64, (BATCH * NTOK) / 64, 1), 256, 0, stream>>>(
        x, FDIM, 0, W0, FDIM, 0, b0, h, HDIM, 0, FDIM, nullptr);
    gemm_nt<1><<<dim3(EDIM / 64, (BATCH * NTOK) / 64, 1), 256, 0, stream>>>(
        h, HDIM, 0, W1, HDIM, 0, b1, e, EDIM, 0, HDIM, nullptr);
    rownorm_kernel<<<dim3((BATCH * NTOK) / 4), 256, 0, stream>>>(e, dvec);
    gemm_nt<2><<<dim3(NTOK / 64, NTOK / 64, BATCH), 256, 0, stream>>>(
        e, EDIM, (size_t)NTOK * EDIM, e, EDIM, (size_t)NTOK * EDIM, nullptr,
        Dm, NTOK, (size_t)NTOK * NTOK, EDIM, dvec);
    sat_row_kernel<<<dim3(NTOK, BATCH), 256, 0, stream>>>(Dm, Sp);
    satc1<<<dim3((NP1 + 255) / 256, 8, BATCH), 256, 0, stream>>>(Sp, aux);
    satc2<<<dim3((NP1 + 255) / 256, BATCH), 256, 0, stream>>>(aux);
    satc3<<<dim3((NP1 + 255) / 256, 8, BATCH), 256, 0, stream>>>(Sp, aux);
    diag_kernel<<<dim3((NP1 + 255) / 256, BATCH), 256, 0, stream>>>(Sp, dg);
    bsum_kernel<<<dim3(NTOK, BATCH), 256, 0, stream>>>(Sp, dg, Dm, CA);

    // Fused DP (cooperative launch for co-residency; spill-free register body).
    void* args[] = { (void*)&Dm, (void*)&CA, (void*)&CB, (void*)&tsum, (void*)&flags };
    hipError_t err = hipLaunchCooperativeKernel((const void*)dp_fused_kernel,
                                                dim3(DP_BX, BATCH), dim3(256),
                                                args, 0, stream);
    if (err != hipSuccess) {
        // fallback: 29 separate step launches (CA already holds C0 from bsum_kernel)
        float* cp = CA; float* cn = CB;
        for (int kk = 1; kk < KSEG; ++kk) {
            dp_step_kernel<<<dim3(128, BATCH), 256, 0, stream>>>(Dm, cp, cn, tsum, kk);
            float* tmp = cp; cp = cn; cn = tmp;
        }
    }
    finalize_kernel<<<dim3(NTOK / 256, BATCH), 256, 0, stream>>>(tsum, out);
}

// Round 13
// 755.796 us; speedup vs baseline: 2.7465x; 1.1074x over previous
//
#include <hip/hip_runtime.h>
#include <hip/hip_bf16.h>
#include <float.h>

// Problem constants (OSG_C_29987461660961)
#define NTOK 2048
#define FDIM 1024
#define HDIM 512
#define EDIM 256
#define BATCH 2
#define KSEG 30
#define NP1 2049
static const size_t ST2 = (size_t)NP1 * NP1;   // Sp per-batch element count

// ---------------------------------------------------------------------------
// NT GEMM (64x64 tile, 4x4 micro) for the two MLP layers.
// MODE 0: bias+relu (h), MODE 1: bias (e)
// ---------------------------------------------------------------------------
template<int MODE>
__global__ __launch_bounds__(256)
void gemm_nt(const float* __restrict__ A, int lda,
             const float* __restrict__ Bm, int ldb,
             const float* __restrict__ bias,
             float* __restrict__ C, int ldc, int K)
{
    __shared__ float As[32][68];
    __shared__ float Bs[32][68];
    const float* Ab = A;
    const float* Bb = Bm;

    const int t = threadIdx.x;
    const int tx = t & 15, ty = t >> 4;
    const int lrow = t >> 3, lkv = t & 7;
    const int by = blockIdx.y, bx = blockIdx.x;

    float acc[4][4] = {};
    const int ktiles = K >> 5;
    for (int kt = 0; kt < ktiles; ++kt) {
#pragma unroll
        for (int h = 0; h < 2; ++h) {
            const int r = lrow + h * 32;
            const float4 av = *(const float4*)(Ab + (size_t)(by * 64 + r) * lda + kt * 32 + lkv * 4);
            As[lkv * 4 + 0][r] = av.x; As[lkv * 4 + 1][r] = av.y;
            As[lkv * 4 + 2][r] = av.z; As[lkv * 4 + 3][r] = av.w;
            const float4 bv = *(const float4*)(Bb + (size_t)(bx * 64 + r) * ldb + kt * 32 + lkv * 4);
            Bs[lkv * 4 + 0][r] = bv.x; Bs[lkv * 4 + 1][r] = bv.y;
            Bs[lkv * 4 + 2][r] = bv.z; Bs[lkv * 4 + 3][r] = bv.w;
        }
        __syncthreads();
#pragma unroll
        for (int kk = 0; kk < 32; ++kk) {
            const float4 a = *(const float4*)&As[kk][ty * 4];
            const float4 b = *(const float4*)&Bs[kk][tx * 4];
            const float ar[4] = {a.x, a.y, a.z, a.w};
            const float br[4] = {b.x, b.y, b.z, b.w};
#pragma unroll
            for (int i = 0; i < 4; ++i)
#pragma unroll
                for (int j = 0; j < 4; ++j)
                    acc[i][j] = fmaf(ar[i], br[j], acc[i][j]);
        }
        __syncthreads();
    }

    const int row0 = by * 64 + ty * 4;
    const int col0 = bx * 64 + tx * 4;
#pragma unroll
    for (int i = 0; i < 4; ++i) {
        float o[4];
#pragma unroll
        for (int j = 0; j < 4; ++j) {
            float v = acc[i][j] + bias[col0 + j];
            if (MODE == 0) v = fmaxf(v, 0.0f);
            o[j] = v;
        }
        float4 v4; v4.x = o[0]; v4.y = o[1]; v4.z = o[2]; v4.w = o[3];
        *(float4*)(C + (size_t)(row0 + i) * ldc + col0) = v4;
    }
}

// ---------------------------------------------------------------------------
// Correlation GEMM + D epilogue: 128x128 tile, BK=16, 8x8 microtile.
// LDS layout uses index padding m' = m + 4*(m>>5) (row width 140) ->
// max 2-way bank aliasing (free) on both b128 reads and scalar writes.
// Per-wave A/B fragment reads are broadcast across 16/4-lane groups.
// ---------------------------------------------------------------------------
__global__ __launch_bounds__(256)
void gemm_corr(const float* __restrict__ E, float* __restrict__ D,
               const float* __restrict__ dvec)
{
    __shared__ float As[16][140];
    __shared__ float Bs[16][140];
    const int z = blockIdx.z;
    const float* Eb = E + (size_t)z * NTOK * EDIM;
    float* Db = D + (size_t)z * NTOK * NTOK;
    const int t = threadIdx.x;
    const int tx = t & 15, ty = t >> 4;
    const int by = blockIdx.y, bx = blockIdx.x;
    const int fq = t & 3, lr = t >> 2;      // loader: float4 idx in k-slice, row

    float acc[8][8] = {};
    for (int kt = 0; kt < EDIM / 16; ++kt) {
#pragma unroll
        for (int h = 0; h < 2; ++h) {
            const int r = lr + h * 64;
            const int rr = r + 4 * (r >> 5);             // padded m index
            const float4 av = *(const float4*)(Eb + (size_t)(by * 128 + r) * EDIM + kt * 16 + fq * 4);
            As[fq * 4 + 0][rr] = av.x; As[fq * 4 + 1][rr] = av.y;
            As[fq * 4 + 2][rr] = av.z; As[fq * 4 + 3][rr] = av.w;
            const float4 bv = *(const float4*)(Eb + (size_t)(bx * 128 + r) * EDIM + kt * 16 + fq * 4);
            Bs[fq * 4 + 0][rr] = bv.x; Bs[fq * 4 + 1][rr] = bv.y;
            Bs[fq * 4 + 2][rr] = bv.z; Bs[fq * 4 + 3][rr] = bv.w;
        }
        __syncthreads();
        const int ma = 8 * ty + 4 * (ty >> 2);           // padded frag bases
        const int mb = 8 * tx + 4 * (tx >> 2);
#pragma unroll
        for (int k = 0; k < 16; ++k) {
            const float4 a0 = *(const float4*)&As[k][ma];
            const float4 a1 = *(const float4*)&As[k][ma + 4];
            const float4 b0 = *(const float4*)&Bs[k][mb];
            const float4 b1 = *(const float4*)&Bs[k][mb + 4];
            const float ar[8] = {a0.x, a0.y, a0.z, a0.w, a1.x, a1.y, a1.z, a1.w};
            const float br[8] = {b0.x, b0.y, b0.z, b0.w, b1.x, b1.y, b1.z, b1.w};
#pragma unroll
            for (int i = 0; i < 8; ++i)
#pragma unroll
                for (int j = 0; j < 8; ++j)
                    acc[i][j] = fmaf(ar[i], br[j], acc[i][j]);
        }
        __syncthreads();
    }

    const int row0 = by * 128 + ty * 8;
    const int col0 = bx * 128 + tx * 8;
    float di[8], dj[8];
#pragma unroll
    for (int i = 0; i < 8; ++i) di[i] = dvec[z * NTOK + row0 + i];
#pragma unroll
    for (int j = 0; j < 8; ++j) dj[j] = dvec[z * NTOK + col0 + j];
#pragma unroll
    for (int i = 0; i < 8; ++i) {
        float o[8];
#pragma unroll
        for (int j = 0; j < 8; ++j) {
            const float den = sqrtf(fmaxf(di[i] * dj[j], 1e-8f));
            o[j] = 0.5f * (1.0f - acc[i][j] / den);
        }
        float4 w0; w0.x = o[0]; w0.y = o[1]; w0.z = o[2]; w0.w = o[3];
        float4 w1; w1.x = o[4]; w1.y = o[5]; w1.z = o[6]; w1.w = o[7];
        *(float4*)(Db + (size_t)(row0 + i) * NTOK + col0) = w0;
        *(float4*)(Db + (size_t)(row0 + i) * NTOK + col0 + 4) = w1;
    }
}

__global__ __launch_bounds__(256)
void rownorm_kernel(const float* __restrict__ e, float* __restrict__ dvec)
{
    const int wid = (blockIdx.x * 256 + threadIdx.x) >> 6;
    const int lane = threadIdx.x & 63;
    if (wid >= BATCH * NTOK) return;
    const float4 v = *(const float4*)(e + (size_t)wid * EDIM + lane * 4);
    float s = v.x * v.x + v.y * v.y + v.z * v.z + v.w * v.w;
#pragma unroll
    for (int off = 32; off; off >>= 1) s += __shfl_xor(s, off);
    if (lane == 0) dvec[wid] = s;
}

// Row-wise inclusive scan of D (f32) into Sp rows 1..N (f64). Sp[r][0]=0.
__global__ __launch_bounds__(256)
void sat_row_kernel(const float* __restrict__ D, double* __restrict__ Sp)
{
    const int b = blockIdx.y;
    const int r = blockIdx.x + 1;
    const float* drow = D + (size_t)b * NTOK * NTOK + (size_t)(r - 1) * NTOK;
    double* sprow = Sp + (size_t)b * ST2 + (size_t)r * NP1;
    const int t = threadIdx.x, lane = t & 63, wv = t >> 6;
    __shared__ double wtot[4];
    double carry = 0.0;
    if (t == 0) sprow[0] = 0.0;
    for (int ch = 0; ch < NTOK / 256; ++ch) {
        double v = (double)drow[ch * 256 + t];
#pragma unroll
        for (int d = 1; d < 64; d <<= 1) {
            const double u = __shfl_up(v, (unsigned)d, 64);
            if (lane >= d) v += u;
        }
        if (lane == 63) wtot[wv] = v;
        __syncthreads();
        double pre = carry;
        for (int ww = 0; ww < wv; ++ww) pre += wtot[ww];
        const double tot = carry + wtot[0] + wtot[1] + wtot[2] + wtot[3];
        sprow[ch * 256 + t + 1] = v + pre;
        __syncthreads();
        carry = tot;
    }
}

// Column cumsum of Sp in 3 phases (strips of 256 rows).
__global__ void satc1(const double* __restrict__ Sp, double* __restrict__ aux)
{
    const int b = blockIdx.z, s = blockIdx.y;
    const int c = blockIdx.x * 256 + threadIdx.x;
    if (c > NTOK) return;
    const double* sp = Sp + (size_t)b * ST2;
    double tt = 0.0;
    const int r0 = s * 256 + 1;
    for (int r = r0; r < r0 + 256; ++r) tt += sp[(size_t)r * NP1 + c];
    aux[(size_t)(b * 8 + s) * NP1 + c] = tt;
}
__global__ void satc2(double* __restrict__ aux)
{
    const int b = blockIdx.y;
    const int c = blockIdx.x * 256 + threadIdx.x;
    if (c > NTOK) return;
    double run = 0.0;
    for (int s = 0; s < 8; ++s) {
        const size_t id = (size_t)(b * 8 + s) * NP1 + c;
        const double tt = aux[id]; aux[id] = run; run += tt;
    }
}
__global__ void satc3(double* __restrict__ Sp, const double* __restrict__ aux)
{
    const int b = blockIdx.z, s = blockIdx.y;
    const int c = blockIdx.x * 256 + threadIdx.x;
    if (c > NTOK) return;
    double* sp = Sp + (size_t)b * ST2;
    if (s == 0) sp[c] = 0.0;
    double run = aux[(size_t)(b * 8 + s) * NP1 + c];
    const int r0 = s * 256 + 1;
    for (int r = r0; r < r0 + 256; ++r) {
        const size_t id = (size_t)r * NP1 + c;
        run += sp[id];
        sp[id] = run;
    }
}

__global__ void diag_kernel(const double* __restrict__ Sp, double* __restrict__ dg)
{
    const int b = blockIdx.y;
    const int t = blockIdx.x * 256 + threadIdx.x;
    if (t <= NTOK) dg[b * NP1 + t] = Sp[(size_t)b * ST2 + (size_t)t * NP1 + t];
}

// Bsum[i][j] = diag[j+1] + diag[i] - 2*Sp[i][j+1] (f64 math -> f32), j >= i.
__global__ __launch_bounds__(256)
void bsum_kernel(const double* __restrict__ Sp, const double* __restrict__ dg,
                 float* __restrict__ Bsum, float* __restrict__ C0)
{
    const int b = blockIdx.y, i = blockIdx.x;
    const double* sprow = Sp + (size_t)b * ST2 + (size_t)i * NP1;
    const double* dgb = dg + (size_t)b * NP1;
    const double di = dgb[i];
    float* brow = Bsum + (size_t)b * NTOK * NTOK + (size_t)i * NTOK;
    for (int j = i + threadIdx.x; j < NTOK; j += 256) {
        const double v = dgb[j + 1] + di - 2.0 * sprow[j + 1];
        brow[j] = (float)v;
        if (j == NTOK - 1) C0[b * NTOK + i] = (float)v;
    }
}

// ---------------------------------------------------------------------------
// DP v9: fence-FREE sync. Everything that crosses blocks (C vectors, flags)
// moves via agent-scope atomics served at the MALL; visibility = store
// completion (vmcnt drained before flag publish). No buffer_inv / wbl2
// anywhere in the step loop.
//   wait    = relaxed parallel flag poll + __syncthreads (compiler barrier)
//   cs fill = b64 agent atomic loads -> LDS
//   publish = vmcnt drain + syncthreads + relaxed agent flag store
// Body: register rb/acc, LDS cs snapshot, pass2 recomputes (no mv spill).
// ---------------------------------------------------------------------------
#define DP_BX 128
#define DP_PAIRS 8
#define RBBIG 3.0e37f

__device__ inline void cstore(float* p, float v)
{
    __hip_atomic_store(p, v, __ATOMIC_RELAXED, __HIP_MEMORY_SCOPE_AGENT);
}

__device__ inline void wait_flags(const int* flagsb, int need)
{
    if (threadIdx.x < DP_BX) {
        const int* f = flagsb + threadIdx.x * 4;
        while (__hip_atomic_load(f, __ATOMIC_RELAXED, __HIP_MEMORY_SCOPE_AGENT) < need)
            __builtin_amdgcn_s_sleep(1);
    }
    __syncthreads();   // full compiler + exec barrier; no cache maintenance
}

__device__ inline void publish(int* myflag, int val)
{
    asm volatile("s_waitcnt vmcnt(0)" ::: "memory");  // C stores complete at MALL
    __syncthreads();
    if (threadIdx.x == 0)
        __hip_atomic_store(myflag, val, __ATOMIC_RELAXED, __HIP_MEMORY_SCOPE_AGENT);
}

// load Bsum row segment into registers (coalesced; OOB -> RBBIG)
template<int NC>
__device__ inline void load_rb(const float* __restrict__ brow, int colbase, int lane,
                               float (&rb)[NC])
{
#pragma unroll
    for (int c = 0; c < NC; ++c) {
        const int col = colbase + lane + c * 64;
        rb[c] = (col < NTOK) ? brow[col] : RBBIG;
    }
}

// pass1: row min of rb + cs (LDS)
template<int NC>
__device__ inline float pass1(const float (&rb)[NC], const float* __restrict__ cs,
                              int coff, int V, int lane)
{
    float mn = FLT_MAX;
#pragma unroll
    for (int c = 0; c < NC; ++c) {
        const int idx = lane + c * 64;
        if (idx < V) mn = fminf(mn, rb[c] + cs[coff + idx]);
    }
#pragma unroll
    for (int o = 32; o; o >>= 1) mn = fminf(mn, __shfl_xor(mn, o));
    return mn;
}

// pass2: recompute values from rb + cs (LDS), softmax, accumulate into reg acc
template<int NC>
__device__ inline void pass2(const float (&rb)[NC], const float* __restrict__ cs,
                             int coff, int V, float mn, int lane, float (&ac)[NC])
{
    float w[NC];
    float s = 0.0f;
#pragma unroll
    for (int c = 0; c < NC; ++c) {
        const int idx = lane + c * 64;
        float x = 0.0f;
        if (idx < V) x = __expf(mn - (rb[c] + cs[coff + idx]));
        w[c] = x;
        s += x;
    }
#pragma unroll
    for (int o = 32; o; o >>= 1) s += __shfl_xor(s, o);
    const float inv = 1.0f / s;
#pragma unroll
    for (int c = 0; c < NC; ++c) ac[c] = __builtin_fmaf(w[c], inv, ac[c]);
}

template<int NC>
__device__ inline void merge_acc(const float (&ac)[NC], int base, int lane,
                                 float* __restrict__ acc_lds)
{
#pragma unroll
    for (int c = 0; c < NC; ++c) {
        const int col = base + lane + c * 64;
        if (col < NTOK && ac[c] != 0.0f) atomicAdd(&acc_lds[col], ac[c]);
    }
}

__global__ __launch_bounds__(256, 1)
void dp_fused_kernel(const float* __restrict__ Bsum,
                     float* __restrict__ Ca, float* __restrict__ Cb,
                     float* __restrict__ tsum, int* __restrict__ flags)
{
    __shared__ float cs[NTOK];
    __shared__ float acc_lds[NTOK];
    const int b = blockIdx.y;
    const int t = threadIdx.x, lane = t & 63, wv = t >> 6;
    const float* Bb = Bsum + (size_t)b * NTOK * NTOK;
    const int pbase = blockIdx.x * DP_PAIRS;
    int* flagsb = flags + b * DP_BX * 4;
    int* myflag = flagsb + blockIdx.x * 4;

    const int p0 = pbase + wv * 2, p1 = p0 + 1;
    const int i1_0 = NTOK - 1 - p0, i1_1 = NTOK - 1 - p1;

    // ---- one-time register load of Bsum pair rows (coalesced) ----
    float rbA0[32], rbB0[16], rbA1[32], rbB1[16];
    load_rb<32>(Bb + (size_t)p0 * NTOK, p0, lane, rbA0);
    load_rb<16>(Bb + (size_t)i1_0 * NTOK, i1_0, lane, rbB0);
    load_rb<32>(Bb + (size_t)p1 * NTOK, p1, lane, rbA1);
    load_rb<16>(Bb + (size_t)i1_1 * NTOK, i1_1, lane, rbB1);

    float acA0[32] = {}, acB0[16] = {}, acA1[32] = {}, acB1[16] = {};

    for (int j = t; j < NTOK; j += 256) acc_lds[j] = 0.0f;

    // ---- C0 (shifted): Csh[i-1] = Bsum[i][N-1] ----
    if (t < DP_PAIRS) {
        const int p = pbase + t, i1 = NTOK - 1 - p;
        if (p > 0) cstore(&Ca[b * NTOK + p - 1], Bb[(size_t)p * NTOK + NTOK - 1]);
        cstore(&Ca[b * NTOK + i1 - 1], Bb[(size_t)i1 * NTOK + NTOK - 1]);
    }
    publish(myflag, 0);

    const float* Cr = Ca;
    float* Cn = Cb;

    for (int k = 1; k < KSEG; ++k) {
        wait_flags(flagsb, k - 1);
        // cs snapshot via b64 agent atomic loads (uncached; fence-free)
        {
            const unsigned long long* Cr8 = (const unsigned long long*)(Cr + b * NTOK);
            unsigned long long* cs8 = (unsigned long long*)cs;
#pragma unroll
            for (int r = 0; r < NTOK / 2 / 256; ++r)
                cs8[t + r * 256] = __hip_atomic_load(&Cr8[t + r * 256],
                                                     __ATOMIC_RELAXED, __HIP_MEMORY_SCOPE_AGENT);
        }
        __syncthreads();
        float* Cnb = Cn + b * NTOK;
        const int jmax = NTOK - k;

        // ---- min phase ----
        const int VA0 = jmax - p0, VA1 = jmax - p1;
        const int VB0 = p0 + 1 - k, VB1 = p1 + 1 - k;
        const float mnA0 = pass1<32>(rbA0, cs, p0, VA0, lane);
        float mnB0 = 0.0f, mnB1 = 0.0f;
        if (p0 >= k) mnB0 = pass1<16>(rbB0, cs, i1_0, VB0, lane);
        const float mnA1 = pass1<32>(rbA1, cs, p1, VA1, lane);
        if (p1 >= k) mnB1 = pass1<16>(rbB1, cs, i1_1, VB1, lane);
        if (lane == 0) {
            if (p0 > 0) cstore(&Cnb[p0 - 1], mnA0);
            cstore(&Cnb[i1_0 - 1], (p0 >= k) ? mnB0 : 0.0f);
            cstore(&Cnb[p1 - 1], mnA1);
            cstore(&Cnb[i1_1 - 1], (p1 >= k) ? mnB1 : 0.0f);
        }
        publish(myflag, k);   // early: pass2 uses only LDS cs + registers

        // ---- exp/accumulate phase (sync shadow; cs stable until next fill) ----
        pass2<32>(rbA0, cs, p0, VA0, mnA0, lane, acA0);
        if (p0 >= k) pass2<16>(rbB0, cs, i1_0, VB0, mnB0, lane, acB0);
        pass2<32>(rbA1, cs, p1, VA1, mnA1, lane, acA1);
        if (p1 >= k) pass2<16>(rbB1, cs, i1_1, VB1, mnB1, lane, acB1);

        float* tmp = (float*)Cr; Cr = Cn; Cn = tmp;
    }

    // ---- one-time merge: regs -> LDS -> global tsum ----
    __syncthreads();
    merge_acc<32>(acA0, p0, lane, acc_lds);
    merge_acc<16>(acB0, i1_0, lane, acc_lds);
    merge_acc<32>(acA1, p1, lane, acc_lds);
    merge_acc<16>(acB1, i1_1, lane, acc_lds);
    __syncthreads();
    float* ts = tsum + b * NTOK;
    for (int j = t; j < NTOK; j += 256) {
        const float v = acc_lds[j];
        if (v != 0.0f) atomicAdd(&ts[j], v);
    }
}

// ---- fallback path (29 launches), kept in case cooperative launch fails ----
// (uses UNSHIFTED C vectors; CA holds unshifted C0 from bsum_kernel)
__global__ __launch_bounds__(256)
void dp_step_kernel(const float* __restrict__ Bsum, const float* __restrict__ Cprev,
                    float* __restrict__ Cnext, float* __restrict__ tsum, int kk)
{
    __shared__ float cs[NTOK];
    __shared__ float acc[NTOK];
    const int b = blockIdx.y;
    const int t = threadIdx.x, lane = t & 63, wv = t >> 6;
    const float* Cp = Cprev + b * NTOK;
    for (int j = t; j < NTOK; j += 256) {
        cs[j] = (j < NTOK - 1) ? Cp[j + 1] : 0.0f;
        acc[j] = 0.0f;
    }
    __syncthreads();
    const int jmax = NTOK - kk;
    const int w = blockIdx.x * 4 + wv;
    const float* Bb = Bsum + (size_t)b * NTOK * NTOK;
    float* Cn = Cnext + b * NTOK;
    const int rows[4] = { w, 1023 - w, 1024 + w, 2047 - w };
#pragma unroll
    for (int rr = 0; rr < 4; ++rr) {
        const int i = rows[rr];
        if (i >= jmax) { if (lane == 0) Cn[i] = 0.0f; continue; }
        const float* brow = Bb + (size_t)i * NTOK;
        const int j0 = i + lane;
        float mv[32];
        float mn = FLT_MAX;
#pragma unroll
        for (int c = 0; c < 32; ++c) {
            const int j = j0 + c * 64;
            float v = FLT_MAX;
            if (j < jmax) v = brow[j] + cs[j];
            mv[c] = v;
            mn = fminf(mn, v);
        }
#pragma unroll
        for (int off = 32; off; off >>= 1) mn = fminf(mn, __shfl_xor(mn, off));
        if (lane == 0) Cn[i] = mn;
        float s = 0.0f;
#pragma unroll
        for (int c = 0; c < 32; ++c) {
            const int j = j0 + c * 64;
            float p = 0.0f;
            if (j < jmax) p = __expf(mn - mv[c]);
            mv[c] = p;
            s += p;
        }
#pragma unroll
        for (int off = 32; off; off >>= 1) s += __shfl_xor(s, off);
        const float inv = 1.0f / s;
#pragma unroll
        for (int c = 0; c < 32; ++c) {
            const int j = j0 + c * 64;
            if (j < jmax) atomicAdd(&acc[j], mv[c] * inv);
        }
    }
    __syncthreads();
    float* ts = tsum + b * NTOK;
    for (int j = t; j < NTOK; j += 256) {
        const float v = acc[j];
        if (v != 0.0f) atomicAdd(&ts[j], v);
    }
}

__global__ void finalize_kernel(const float* __restrict__ tsum, float* __restrict__ out)
{
    const int b = blockIdx.y;
    const int j = blockIdx.x * 256 + threadIdx.x;
    if (j >= NTOK) return;
    float ts = tsum[b * NTOK + j];
    int steps = NTOK - 1 - j;
    if (steps > KSEG - 1) steps = KSEG - 1;
    float tc = (float)(j + 1) * (float)steps;
    if (j == NTOK - 1) { ts += (float)NTOK; tc += (float)NTOK; }
    out[b * NTOK + j] = ts / tc;
}

extern "C" void kernel_launch(void* const* d_in, const int* in_sizes, int n_in,
                              void* d_out, int out_size, void* d_ws, size_t ws_size,
                              hipStream_t stream)
{
    const float* x  = (const float*)d_in[0];
    const float* W0 = (const float*)d_in[1];
    const float* b0 = (const float*)d_in[2];
    const float* W1 = (const float*)d_in[3];
    const float* b1 = (const float*)d_in[4];
    float* out = (float*)d_out;

    char* ws = (char*)d_ws;
    size_t off = 0;
    auto alloc = [&](size_t bytes) -> void* {
        void* p = (void*)(ws + off);
        off += (bytes + 255) & ~(size_t)255;
        return p;
    };
    double* Sp   = (double*)alloc((size_t)BATCH * ST2 * sizeof(double));
    float*  Dm   = (float*) alloc((size_t)BATCH * NTOK * NTOK * sizeof(float));
    float*  h    = (float*) alloc((size_t)BATCH * NTOK * HDIM * sizeof(float));
    float*  e    = (float*) alloc((size_t)BATCH * NTOK * EDIM * sizeof(float));
    float*  dvec = (float*) alloc((size_t)BATCH * NTOK * sizeof(float));
    double* dg   = (double*)alloc((size_t)BATCH * NP1 * sizeof(double));
    double* aux  = (double*)alloc((size_t)BATCH * 8 * NP1 * sizeof(double));
    float*  CA   = (float*) alloc((size_t)BATCH * NTOK * sizeof(float));
    float*  CB   = (float*) alloc((size_t)BATCH * NTOK * sizeof(float));
    float*  tsum = (float*) alloc((size_t)BATCH * NTOK * sizeof(float));
    int*    flags= (int*)   alloc((size_t)BATCH * DP_BX * 4 * sizeof(int));
    (void)ws_size; (void)in_sizes; (void)n_in; (void)out_size;

    hipMemsetAsync(tsum, 0, (size_t)BATCH * NTOK * sizeof(float), stream);
    hipMemsetAsync(flags, 0xFF, (size_t)BATCH * DP_BX * 4 * sizeof(int), stream);  // -1

    // h = relu(x @ W0^T + b0)   [4096 x 512]
    gemm_nt<0><<<dim3(HDIM / 64, (BATCH * NTOK) / 64), 256, 0, stream>>>(
        x, FDIM, W0, FDIM, b0, h, HDIM, FDIM);
    // e = h @ W1^T + b1         [4096 x 256]
    gemm_nt<1><<<dim3(EDIM / 64, (BATCH * NTOK) / 64), 256, 0, stream>>>(
        h, HDIM, W1, HDIM, b1, e, EDIM, HDIM);
    rownorm_kernel<<<dim3((BATCH * NTOK) / 4), 256, 0, stream>>>(e, dvec);
    // D from correlation (128x128 tile, 8x8 micro)
    gemm_corr<<<dim3(NTOK / 128, NTOK / 128, BATCH), 256, 0, stream>>>(e, Dm, dvec);
    sat_row_kernel<<<dim3(NTOK, BATCH), 256, 0, stream>>>(Dm, Sp);
    satc1<<<dim3((NP1 + 255) / 256, 8, BATCH), 256, 0, stream>>>(Sp, aux);
    satc2<<<dim3((NP1 + 255) / 256, BATCH), 256, 0, stream>>>(aux);
    satc3<<<dim3((NP1 + 255) / 256, 8, BATCH), 256, 0, stream>>>(Sp, aux);
    diag_kernel<<<dim3((NP1 + 255) / 256, BATCH), 256, 0, stream>>>(Sp, dg);
    bsum_kernel<<<dim3(NTOK, BATCH), 256, 0, stream>>>(Sp, dg, Dm, CA);

    // Fused DP (cooperative launch for co-residency; fence-free sync).
    void* args[] = { (void*)&Dm, (void*)&CA, (void*)&CB, (void*)&tsum, (void*)&flags };
    hipError_t err = hipLaunchCooperativeKernel((const void*)dp_fused_kernel,
                                                dim3(DP_BX, BATCH), dim3(256),
                                                args, 0, stream);
    if (err != hipSuccess) {
        // fallback: 29 separate step launches (CA already holds C0 from bsum_kernel)
        float* cp = CA; float* cn = CB;
        for (int kk = 1; kk < KSEG; ++kk) {
            dp_step_kernel<<<dim3(128, BATCH), 256, 0, stream>>>(Dm, cp, cn, tsum, kk);
            float* tmp = cp; cp = cn; cn = tmp;
        }
    }
    finalize_kernel<<<dim3(NTOK / 256, BATCH), 256, 0, stream>>>(tsum, out);
}

// Round 14
// 739.434 us; speedup vs baseline: 2.8073x; 1.0221x over previous
//
#include <hip/hip_runtime.h>
#include <hip/hip_bf16.h>
#include <float.h>

// Problem constants (OSG_C_29987461660961)
#define NTOK 2048
#define FDIM 1024
#define HDIM 512
#define EDIM 256
#define BATCH 2
#define KSEG 30
#define NP1 2049
static const size_t ST2 = (size_t)NP1 * NP1;   // Sp per-batch element count

// ---------------------------------------------------------------------------
// NT GEMM (64x64 tile, 4x4 micro) — layer 1 only (N=256 too small for 128-tile)
// ---------------------------------------------------------------------------
__global__ __launch_bounds__(256)
void gemm_nt64(const float* __restrict__ A, int lda,
               const float* __restrict__ Bm, int ldb,
               const float* __restrict__ bias,
               float* __restrict__ C, int ldc, int K)
{
    __shared__ float As[32][68];
    __shared__ float Bs[32][68];
    const int t = threadIdx.x;
    const int tx = t & 15, ty = t >> 4;
    const int lrow = t >> 3, lkv = t & 7;
    const int by = blockIdx.y, bx = blockIdx.x;

    float acc[4][4] = {};
    const int ktiles = K >> 5;
    for (int kt = 0; kt < ktiles; ++kt) {
#pragma unroll
        for (int h = 0; h < 2; ++h) {
            const int r = lrow + h * 32;
            const float4 av = *(const float4*)(A + (size_t)(by * 64 + r) * lda + kt * 32 + lkv * 4);
            As[lkv * 4 + 0][r] = av.x; As[lkv * 4 + 1][r] = av.y;
            As[lkv * 4 + 2][r] = av.z; As[lkv * 4 + 3][r] = av.w;
            const float4 bv = *(const float4*)(Bm + (size_t)(bx * 64 + r) * ldb + kt * 32 + lkv * 4);
            Bs[lkv * 4 + 0][r] = bv.x; Bs[lkv * 4 + 1][r] = bv.y;
            Bs[lkv * 4 + 2][r] = bv.z; Bs[lkv * 4 + 3][r] = bv.w;
        }
        __syncthreads();
#pragma unroll
        for (int kk = 0; kk < 32; ++kk) {
            const float4 a = *(const float4*)&As[kk][ty * 4];
            const float4 b = *(const float4*)&Bs[kk][tx * 4];
            const float ar[4] = {a.x, a.y, a.z, a.w};
            const float br[4] = {b.x, b.y, b.z, b.w};
#pragma unroll
            for (int i = 0; i < 4; ++i)
#pragma unroll
                for (int j = 0; j < 4; ++j)
                    acc[i][j] = fmaf(ar[i], br[j], acc[i][j]);
        }
        __syncthreads();
    }

    const int row0 = by * 64 + ty * 4;
    const int col0 = bx * 64 + tx * 4;
#pragma unroll
    for (int i = 0; i < 4; ++i) {
        float4 v4;
        v4.x = acc[i][0] + bias[col0 + 0];
        v4.y = acc[i][1] + bias[col0 + 1];
        v4.z = acc[i][2] + bias[col0 + 2];
        v4.w = acc[i][3] + bias[col0 + 3];
        *(float4*)(C + (size_t)(row0 + i) * ldc + col0) = v4;
    }
}

// ---------------------------------------------------------------------------
// Split-K 128x128 / 8x8 GEMM partial for layer 0 (x @ W0^T), no epilogue.
// grid (N/128, M/128, SPLITS); partial s at Cp + s*M*ldc.
// ---------------------------------------------------------------------------
__global__ __launch_bounds__(256)
void gemm_nt128s(const float* __restrict__ A, int lda,
                 const float* __restrict__ Bm, int ldb,
                 float* __restrict__ Cp, int ldc, int M, int khalf)
{
    __shared__ float As[16][140];
    __shared__ float Bs[16][140];
    const int t = threadIdx.x;
    const int tx = t & 15, ty = t >> 4;
    const int by = blockIdx.y, bx = blockIdx.x;
    const int k0 = blockIdx.z * khalf;
    const int fq = t & 3, lr = t >> 2;

    float acc[8][8] = {};
    for (int kt = 0; kt < khalf / 16; ++kt) {
#pragma unroll
        for (int h = 0; h < 2; ++h) {
            const int r = lr + h * 64;
            const int rr = r + 4 * (r >> 5);
            const float4 av = *(const float4*)(A + (size_t)(by * 128 + r) * lda + k0 + kt * 16 + fq * 4);
            As[fq * 4 + 0][rr] = av.x; As[fq * 4 + 1][rr] = av.y;
            As[fq * 4 + 2][rr] = av.z; As[fq * 4 + 3][rr] = av.w;
            const float4 bv = *(const float4*)(Bm + (size_t)(bx * 128 + r) * ldb + k0 + kt * 16 + fq * 4);
            Bs[fq * 4 + 0][rr] = bv.x; Bs[fq * 4 + 1][rr] = bv.y;
            Bs[fq * 4 + 2][rr] = bv.z; Bs[fq * 4 + 3][rr] = bv.w;
        }
        __syncthreads();
        const int ma = 8 * ty + 4 * (ty >> 2);
        const int mb = 8 * tx + 4 * (tx >> 2);
#pragma unroll
        for (int k = 0; k < 16; ++k) {
            const float4 a0 = *(const float4*)&As[k][ma];
            const float4 a1 = *(const float4*)&As[k][ma + 4];
            const float4 b0 = *(const float4*)&Bs[k][mb];
            const float4 b1 = *(const float4*)&Bs[k][mb + 4];
            const float ar[8] = {a0.x, a0.y, a0.z, a0.w, a1.x, a1.y, a1.z, a1.w};
            const float br[8] = {b0.x, b0.y, b0.z, b0.w, b1.x, b1.y, b1.z, b1.w};
#pragma unroll
            for (int i = 0; i < 8; ++i)
#pragma unroll
                for (int j = 0; j < 8; ++j)
                    acc[i][j] = fmaf(ar[i], br[j], acc[i][j]);
        }
        __syncthreads();
    }

    float* outp = Cp + (size_t)blockIdx.z * M * ldc;
    const int row0 = by * 128 + ty * 8;
    const int col0 = bx * 128 + tx * 8;
#pragma unroll
    for (int i = 0; i < 8; ++i) {
        float4 w0; w0.x = acc[i][0]; w0.y = acc[i][1]; w0.z = acc[i][2]; w0.w = acc[i][3];
        float4 w1; w1.x = acc[i][4]; w1.y = acc[i][5]; w1.z = acc[i][6]; w1.w = acc[i][7];
        *(float4*)(outp + (size_t)(row0 + i) * ldc + col0) = w0;
        *(float4*)(outp + (size_t)(row0 + i) * ldc + col0 + 4) = w1;
    }
}

// h = relu(p0 + p1 + bias)   (layer-0 split-K combine; N=512)
__global__ __launch_bounds__(256)
void combine_relu(const float* __restrict__ p0, const float* __restrict__ p1,
                  const float* __restrict__ bias, float* __restrict__ hout)
{
    const int idx = blockIdx.x * 256 + threadIdx.x;     // float4 index
    const float4 a = ((const float4*)p0)[idx];
    const float4 b = ((const float4*)p1)[idx];
    const float4 bs = *(const float4*)&bias[(idx & 127) * 4];
    float4 o;
    o.x = fmaxf(a.x + b.x + bs.x, 0.0f);
    o.y = fmaxf(a.y + b.y + bs.y, 0.0f);
    o.z = fmaxf(a.z + b.z + bs.z, 0.0f);
    o.w = fmaxf(a.w + b.w + bs.w, 0.0f);
    ((float4*)hout)[idx] = o;
}

// ---------------------------------------------------------------------------
// Correlation GEMM + D epilogue: 128x128 tile, BK=16, 8x8 microtile.
// ---------------------------------------------------------------------------
__global__ __launch_bounds__(256)
void gemm_corr(const float* __restrict__ E, float* __restrict__ D,
               const float* __restrict__ dvec)
{
    __shared__ float As[16][140];
    __shared__ float Bs[16][140];
    const int z = blockIdx.z;
    const float* Eb = E + (size_t)z * NTOK * EDIM;
    float* Db = D + (size_t)z * NTOK * NTOK;
    const int t = threadIdx.x;
    const int tx = t & 15, ty = t >> 4;
    const int by = blockIdx.y, bx = blockIdx.x;
    const int fq = t & 3, lr = t >> 2;

    float acc[8][8] = {};
    for (int kt = 0; kt < EDIM / 16; ++kt) {
#pragma unroll
        for (int h = 0; h < 2; ++h) {
            const int r = lr + h * 64;
            const int rr = r + 4 * (r >> 5);
            const float4 av = *(const float4*)(Eb + (size_t)(by * 128 + r) * EDIM + kt * 16 + fq * 4);
            As[fq * 4 + 0][rr] = av.x; As[fq * 4 + 1][rr] = av.y;
            As[fq * 4 + 2][rr] = av.z; As[fq * 4 + 3][rr] = av.w;
            const float4 bv = *(const float4*)(Eb + (size_t)(bx * 128 + r) * EDIM + kt * 16 + fq * 4);
            Bs[fq * 4 + 0][rr] = bv.x; Bs[fq * 4 + 1][rr] = bv.y;
            Bs[fq * 4 + 2][rr] = bv.z; Bs[fq * 4 + 3][rr] = bv.w;
        }
        __syncthreads();
        const int ma = 8 * ty + 4 * (ty >> 2);
        const int mb = 8 * tx + 4 * (tx >> 2);
#pragma unroll
        for (int k = 0; k < 16; ++k) {
            const float4 a0 = *(const float4*)&As[k][ma];
            const float4 a1 = *(const float4*)&As[k][ma + 4];
            const float4 b0 = *(const float4*)&Bs[k][mb];
            const float4 b1 = *(const float4*)&Bs[k][mb + 4];
            const float ar[8] = {a0.x, a0.y, a0.z, a0.w, a1.x, a1.y, a1.z, a1.w};
            const float br[8] = {b0.x, b0.y, b0.z, b0.w, b1.x, b1.y, b1.z, b1.w};
#pragma unroll
            for (int i = 0; i < 8; ++i)
#pragma unroll
                for (int j = 0; j < 8; ++j)
                    acc[i][j] = fmaf(ar[i], br[j], acc[i][j]);
        }
        __syncthreads();
    }

    const int row0 = by * 128 + ty * 8;
    const int col0 = bx * 128 + tx * 8;
    float di[8], dj[8];
#pragma unroll
    for (int i = 0; i < 8; ++i) di[i] = dvec[z * NTOK + row0 + i];
#pragma unroll
    for (int j = 0; j < 8; ++j) dj[j] = dvec[z * NTOK + col0 + j];
#pragma unroll
    for (int i = 0; i < 8; ++i) {
        float o[8];
#pragma unroll
        for (int j = 0; j < 8; ++j) {
            const float den = sqrtf(fmaxf(di[i] * dj[j], 1e-8f));
            o[j] = 0.5f * (1.0f - acc[i][j] / den);
        }
        float4 w0; w0.x = o[0]; w0.y = o[1]; w0.z = o[2]; w0.w = o[3];
        float4 w1; w1.x = o[4]; w1.y = o[5]; w1.z = o[6]; w1.w = o[7];
        *(float4*)(Db + (size_t)(row0 + i) * NTOK + col0) = w0;
        *(float4*)(Db + (size_t)(row0 + i) * NTOK + col0 + 4) = w1;
    }
}

__global__ __launch_bounds__(256)
void rownorm_kernel(const float* __restrict__ e, float* __restrict__ dvec)
{
    const int wid = (blockIdx.x * 256 + threadIdx.x) >> 6;
    const int lane = threadIdx.x & 63;
    if (wid >= BATCH * NTOK) return;
    const float4 v = *(const float4*)(e + (size_t)wid * EDIM + lane * 4);
    float s = v.x * v.x + v.y * v.y + v.z * v.z + v.w * v.w;
#pragma unroll
    for (int off = 32; off; off >>= 1) s += __shfl_xor(s, off);
    if (lane == 0) dvec[wid] = s;
}

// Row-wise inclusive scan of D (f32) into Sp rows 1..N (f64). Sp[r][0]=0.
__global__ __launch_bounds__(256)
void sat_row_kernel(const float* __restrict__ D, double* __restrict__ Sp)
{
    const int b = blockIdx.y;
    const int r = blockIdx.x + 1;
    const float* drow = D + (size_t)b * NTOK * NTOK + (size_t)(r - 1) * NTOK;
    double* sprow = Sp + (size_t)b * ST2 + (size_t)r * NP1;
    const int t = threadIdx.x, lane = t & 63, wv = t >> 6;
    __shared__ double wtot[4];
    double carry = 0.0;
    if (t == 0) sprow[0] = 0.0;
    for (int ch = 0; ch < NTOK / 256; ++ch) {
        double v = (double)drow[ch * 256 + t];
#pragma unroll
        for (int d = 1; d < 64; d <<= 1) {
            const double u = __shfl_up(v, (unsigned)d, 64);
            if (lane >= d) v += u;
        }
        if (lane == 63) wtot[wv] = v;
        __syncthreads();
        double pre = carry;
        for (int ww = 0; ww < wv; ++ww) pre += wtot[ww];
        const double tot = carry + wtot[0] + wtot[1] + wtot[2] + wtot[3];
        sprow[ch * 256 + t + 1] = v + pre;
        __syncthreads();
        carry = tot;
    }
}

// Column cumsum of Sp in 3 phases (strips of 256 rows).
__global__ void satc1(const double* __restrict__ Sp, double* __restrict__ aux)
{
    const int b = blockIdx.z, s = blockIdx.y;
    const int c = blockIdx.x * 256 + threadIdx.x;
    if (c > NTOK) return;
    const double* sp = Sp + (size_t)b * ST2;
    double tt = 0.0;
    const int r0 = s * 256 + 1;
    for (int r = r0; r < r0 + 256; ++r) tt += sp[(size_t)r * NP1 + c];
    aux[(size_t)(b * 8 + s) * NP1 + c] = tt;
}
__global__ void satc2(double* __restrict__ aux)
{
    const int b = blockIdx.y;
    const int c = blockIdx.x * 256 + threadIdx.x;
    if (c > NTOK) return;
    double run = 0.0;
    for (int s = 0; s < 8; ++s) {
        const size_t id = (size_t)(b * 8 + s) * NP1 + c;
        const double tt = aux[id]; aux[id] = run; run += tt;
    }
}
__global__ void satc3(double* __restrict__ Sp, const double* __restrict__ aux)
{
    const int b = blockIdx.z, s = blockIdx.y;
    const int c = blockIdx.x * 256 + threadIdx.x;
    if (c > NTOK) return;
    double* sp = Sp + (size_t)b * ST2;
    if (s == 0) sp[c] = 0.0;
    double run = aux[(size_t)(b * 8 + s) * NP1 + c];
    const int r0 = s * 256 + 1;
    for (int r = r0; r < r0 + 256; ++r) {
        const size_t id = (size_t)r * NP1 + c;
        run += sp[id];
        sp[id] = run;
    }
}

__global__ void diag_kernel(const double* __restrict__ Sp, double* __restrict__ dg)
{
    const int b = blockIdx.y;
    const int t = blockIdx.x * 256 + threadIdx.x;
    if (t <= NTOK) dg[b * NP1 + t] = Sp[(size_t)b * ST2 + (size_t)t * NP1 + t];
}

// Bsum[i][j] = diag[j+1] + diag[i] - 2*Sp[i][j+1] (f64 math -> f32), j >= i.
__global__ __launch_bounds__(256)
void bsum_kernel(const double* __restrict__ Sp, const double* __restrict__ dg,
                 float* __restrict__ Bsum, float* __restrict__ C0)
{
    const int b = blockIdx.y, i = blockIdx.x;
    const double* sprow = Sp + (size_t)b * ST2 + (size_t)i * NP1;
    const double* dgb = dg + (size_t)b * NP1;
    const double di = dgb[i];
    float* brow = Bsum + (size_t)b * NTOK * NTOK + (size_t)i * NTOK;
    for (int j = i + threadIdx.x; j < NTOK; j += 256) {
        const double v = dgb[j + 1] + di - 2.0 * sprow[j + 1];
        brow[j] = (float)v;
        if (j == NTOK - 1) C0[b * NTOK + i] = (float)v;
    }
}

// ---------------------------------------------------------------------------
// DP v10 = v9 (fence-free, register body) with dwordx4-sc1 cs fill.
// ---------------------------------------------------------------------------
#define DP_BX 128
#define DP_PAIRS 8
#define RBBIG 3.0e37f

__device__ inline void cstore(float* p, float v)
{
    __hip_atomic_store(p, v, __ATOMIC_RELAXED, __HIP_MEMORY_SCOPE_AGENT);
}

__device__ inline void wait_flags(const int* flagsb, int need)
{
    if (threadIdx.x < DP_BX) {
        const int* f = flagsb + threadIdx.x * 4;
        while (__hip_atomic_load(f, __ATOMIC_RELAXED, __HIP_MEMORY_SCOPE_AGENT) < need)
            __builtin_amdgcn_s_sleep(1);
    }
    __syncthreads();   // full compiler + exec barrier; no cache maintenance
}

__device__ inline void publish(int* myflag, int val)
{
    asm volatile("s_waitcnt vmcnt(0)" ::: "memory");  // C stores complete at MALL
    __syncthreads();
    if (threadIdx.x == 0)
        __hip_atomic_store(myflag, val, __ATOMIC_RELAXED, __HIP_MEMORY_SCOPE_AGENT);
}

template<int NC>
__device__ inline void load_rb(const float* __restrict__ brow, int colbase, int lane,
                               float (&rb)[NC])
{
#pragma unroll
    for (int c = 0; c < NC; ++c) {
        const int col = colbase + lane + c * 64;
        rb[c] = (col < NTOK) ? brow[col] : RBBIG;
    }
}

template<int NC>
__device__ inline float pass1(const float (&rb)[NC], const float* __restrict__ cs,
                              int coff, int V, int lane)
{
    float mn = FLT_MAX;
#pragma unroll
    for (int c = 0; c < NC; ++c) {
        const int idx = lane + c * 64;
        if (idx < V) mn = fminf(mn, rb[c] + cs[coff + idx]);
    }
#pragma unroll
    for (int o = 32; o; o >>= 1) mn = fminf(mn, __shfl_xor(mn, o));
    return mn;
}

template<int NC>
__device__ inline void pass2(const float (&rb)[NC], const float* __restrict__ cs,
                             int coff, int V, float mn, int lane, float (&ac)[NC])
{
    float w[NC];
    float s = 0.0f;
#pragma unroll
    for (int c = 0; c < NC; ++c) {
        const int idx = lane + c * 64;
        float x = 0.0f;
        if (idx < V) x = __expf(mn - (rb[c] + cs[coff + idx]));
        w[c] = x;
        s += x;
    }
#pragma unroll
    for (int o = 32; o; o >>= 1) s += __shfl_xor(s, o);
    const float inv = 1.0f / s;
#pragma unroll
    for (int c = 0; c < NC; ++c) ac[c] = __builtin_fmaf(w[c], inv, ac[c]);
}

template<int NC>
__device__ inline void merge_acc(const float (&ac)[NC], int base, int lane,
                                 float* __restrict__ acc_lds)
{
#pragma unroll
    for (int c = 0; c < NC; ++c) {
        const int col = base + lane + c * 64;
        if (col < NTOK && ac[c] != 0.0f) atomicAdd(&acc_lds[col], ac[c]);
    }
}

__global__ __launch_bounds__(256, 1)
void dp_fused_kernel(const float* __restrict__ Bsum,
                     float* __restrict__ Ca, float* __restrict__ Cb,
                     float* __restrict__ tsum, int* __restrict__ flags)
{
    __shared__ float cs[NTOK];
    __shared__ float acc_lds[NTOK];
    const int b = blockIdx.y;
    const int t = threadIdx.x, lane = t & 63, wv = t >> 6;
    const float* Bb = Bsum + (size_t)b * NTOK * NTOK;
    const int pbase = blockIdx.x * DP_PAIRS;
    int* flagsb = flags + b * DP_BX * 4;
    int* myflag = flagsb + blockIdx.x * 4;

    const int p0 = pbase + wv * 2, p1 = p0 + 1;
    const int i1_0 = NTOK - 1 - p0, i1_1 = NTOK - 1 - p1;

    // ---- one-time register load of Bsum pair rows (coalesced) ----
    float rbA0[32], rbB0[16], rbA1[32], rbB1[16];
    load_rb<32>(Bb + (size_t)p0 * NTOK, p0, lane, rbA0);
    load_rb<16>(Bb + (size_t)i1_0 * NTOK, i1_0, lane, rbB0);
    load_rb<32>(Bb + (size_t)p1 * NTOK, p1, lane, rbA1);
    load_rb<16>(Bb + (size_t)i1_1 * NTOK, i1_1, lane, rbB1);

    float acA0[32] = {}, acB0[16] = {}, acA1[32] = {}, acB1[16] = {};

    for (int j = t; j < NTOK; j += 256) acc_lds[j] = 0.0f;

    // ---- C0 (shifted): Csh[i-1] = Bsum[i][N-1] ----
    if (t < DP_PAIRS) {
        const int p = pbase + t, i1 = NTOK - 1 - p;
        if (p > 0) cstore(&Ca[b * NTOK + p - 1], Bb[(size_t)p * NTOK + NTOK - 1]);
        cstore(&Ca[b * NTOK + i1 - 1], Bb[(size_t)i1 * NTOK + NTOK - 1]);
    }
    publish(myflag, 0);

    const float* Cr = Ca;
    float* Cn = Cb;

    for (int k = 1; k < KSEG; ++k) {
        wait_flags(flagsb, k - 1);
        // cs snapshot: 2x global_load_dwordx4 sc1 (MALL-coherent, fence-free)
        {
            const float* base  = Cr + b * NTOK + t * 4;
            const float* base2 = base + 1024;
            float4 va, vb;
            asm volatile(
                "global_load_dwordx4 %0, %2, off sc1\n\t"
                "global_load_dwordx4 %1, %3, off sc1\n\t"
                "s_waitcnt vmcnt(0)"
                : "=&v"(va), "=&v"(vb)
                : "v"(base), "v"(base2)
                : "memory");
            *(float4*)&cs[t * 4] = va;
            *(float4*)&cs[t * 4 + 1024] = vb;
        }
        __syncthreads();
        float* Cnb = Cn + b * NTOK;
        const int jmax = NTOK - k;

        // ---- min phase ----
        const int VA0 = jmax - p0, VA1 = jmax - p1;
        const int VB0 = p0 + 1 - k, VB1 = p1 + 1 - k;
        const float mnA0 = pass1<32>(rbA0, cs, p0, VA0, lane);
        float mnB0 = 0.0f, mnB1 = 0.0f;
        if (p0 >= k) mnB0 = pass1<16>(rbB0, cs, i1_0, VB0, lane);
        const float mnA1 = pass1<32>(rbA1, cs, p1, VA1, lane);
        if (p1 >= k) mnB1 = pass1<16>(rbB1, cs, i1_1, VB1, lane);
        if (lane == 0) {
            if (p0 > 0) cstore(&Cnb[p0 - 1], mnA0);
            cstore(&Cnb[i1_0 - 1], (p0 >= k) ? mnB0 : 0.0f);
            cstore(&Cnb[p1 - 1], mnA1);
            cstore(&Cnb[i1_1 - 1], (p1 >= k) ? mnB1 : 0.0f);
        }
        publish(myflag, k);   // early: pass2 uses only LDS cs + registers

        // ---- exp/accumulate phase (sync shadow; cs stable until next fill) ----
        pass2<32>(rbA0, cs, p0, VA0, mnA0, lane, acA0);
        if (p0 >= k) pass2<16>(rbB0, cs, i1_0, VB0, mnB0, lane, acB0);
        pass2<32>(rbA1, cs, p1, VA1, mnA1, lane, acA1);
        if (p1 >= k) pass2<16>(rbB1, cs, i1_1, VB1, mnB1, lane, acB1);

        float* tmp = (float*)Cr; Cr = Cn; Cn = tmp;
    }

    // ---- one-time merge: regs -> LDS -> global tsum ----
    __syncthreads();
    merge_acc<32>(acA0, p0, lane, acc_lds);
    merge_acc<16>(acB0, i1_0, lane, acc_lds);
    merge_acc<32>(acA1, p1, lane, acc_lds);
    merge_acc<16>(acB1, i1_1, lane, acc_lds);
    __syncthreads();
    float* ts = tsum + b * NTOK;
    for (int j = t; j < NTOK; j += 256) {
        const float v = acc_lds[j];
        if (v != 0.0f) atomicAdd(&ts[j], v);
    }
}

// ---- fallback path (29 launches), kept in case cooperative launch fails ----
__global__ __launch_bounds__(256)
void dp_step_kernel(const float* __restrict__ Bsum, const float* __restrict__ Cprev,
                    float* __restrict__ Cnext, float* __restrict__ tsum, int kk)
{
    __shared__ float cs[NTOK];
    __shared__ float acc[NTOK];
    const int b = blockIdx.y;
    const int t = threadIdx.x, lane = t & 63, wv = t >> 6;
    const float* Cp = Cprev + b * NTOK;
    for (int j = t; j < NTOK; j += 256) {
        cs[j] = (j < NTOK - 1) ? Cp[j + 1] : 0.0f;
        acc[j] = 0.0f;
    }
    __syncthreads();
    const int jmax = NTOK - kk;
    const int w = blockIdx.x * 4 + wv;
    const float* Bb = Bsum + (size_t)b * NTOK * NTOK;
    float* Cn = Cnext + b * NTOK;
    const int rows[4] = { w, 1023 - w, 1024 + w, 2047 - w };
#pragma unroll
    for (int rr = 0; rr < 4; ++rr) {
        const int i = rows[rr];
        if (i >= jmax) { if (lane == 0) Cn[i] = 0.0f; continue; }
        const float* brow = Bb + (size_t)i * NTOK;
        const int j0 = i + lane;
        float mv[32];
        float mn = FLT_MAX;
#pragma unroll
        for (int c = 0; c < 32; ++c) {
            const int j = j0 + c * 64;
            float v = FLT_MAX;
            if (j < jmax) v = brow[j] + cs[j];
            mv[c] = v;
            mn = fminf(mn, v);
        }
#pragma unroll
        for (int off = 32; off; off >>= 1) mn = fminf(mn, __shfl_xor(mn, off));
        if (lane == 0) Cn[i] = mn;
        float s = 0.0f;
#pragma unroll
        for (int c = 0; c < 32; ++c) {
            const int j = j0 + c * 64;
            float p = 0.0f;
            if (j < jmax) p = __expf(mn - mv[c]);
            mv[c] = p;
            s += p;
        }
#pragma unroll
        for (int off = 32; off; off >>= 1) s += __shfl_xor(s, off);
        const float inv = 1.0f / s;
#pragma unroll
        for (int c = 0; c < 32; ++c) {
            const int j = j0 + c * 64;
            if (j < jmax) atomicAdd(&acc[j], mv[c] * inv);
        }
    }
    __syncthreads();
    float* ts = tsum + b * NTOK;
    for (int j = t; j < NTOK; j += 256) {
        const float v = acc[j];
        if (v != 0.0f) atomicAdd(&ts[j], v);
    }
}

__global__ void finalize_kernel(const float* __restrict__ tsum, float* __restrict__ out)
{
    const int b = blockIdx.y;
    const int j = blockIdx.x * 256 + threadIdx.x;
    if (j >= NTOK) return;
    float ts = tsum[b * NTOK + j];
    int steps = NTOK - 1 - j;
    if (steps > KSEG - 1) steps = KSEG - 1;
    float tc = (float)(j + 1) * (float)steps;
    if (j == NTOK - 1) { ts += (float)NTOK; tc += (float)NTOK; }
    out[b * NTOK + j] = ts / tc;
}

extern "C" void kernel_launch(void* const* d_in, const int* in_sizes, int n_in,
                              void* d_out, int out_size, void* d_ws, size_t ws_size,
                              hipStream_t stream)
{
    const float* x  = (const float*)d_in[0];
    const float* W0 = (const float*)d_in[1];
    const float* b0 = (const float*)d_in[2];
    const float* W1 = (const float*)d_in[3];
    const float* b1 = (const float*)d_in[4];
    float* out = (float*)d_out;

    char* ws = (char*)d_ws;
    size_t off = 0;
    auto alloc = [&](size_t bytes) -> void* {
        void* p = (void*)(ws + off);
        off += (bytes + 255) & ~(size_t)255;
        return p;
    };
    double* Sp   = (double*)alloc((size_t)BATCH * ST2 * sizeof(double));
    float*  Dm   = (float*) alloc((size_t)BATCH * NTOK * NTOK * sizeof(float));   // also hosts layer-0 split-K partials
    float*  h    = (float*) alloc((size_t)BATCH * NTOK * HDIM * sizeof(float));
    float*  e    = (float*) alloc((size_t)BATCH * NTOK * EDIM * sizeof(float));
    float*  dvec = (float*) alloc((size_t)BATCH * NTOK * sizeof(float));
    double* dg   = (double*)alloc((size_t)BATCH * NP1 * sizeof(double));
    double* aux  = (double*)alloc((size_t)BATCH * 8 * NP1 * sizeof(double));
    float*  CA   = (float*) alloc((size_t)BATCH * NTOK * sizeof(float));
    float*  CB   = (float*) alloc((size_t)BATCH * NTOK * sizeof(float));
    float*  tsum = (float*) alloc((size_t)BATCH * NTOK * sizeof(float));
    int*    flags= (int*)   alloc((size_t)BATCH * DP_BX * 4 * sizeof(int));
    (void)ws_size; (void)in_sizes; (void)n_in; (void)out_size;

    hipMemsetAsync(tsum, 0, (size_t)BATCH * NTOK * sizeof(float), stream);
    hipMemsetAsync(flags, 0xFF, (size_t)BATCH * DP_BX * 4 * sizeof(int), stream);  // -1

    // Layer 0 (split-K=2, partials in Dm region): h = relu(x @ W0^T + b0)
    float* Hpart = Dm;    // 2 * 4096*512 f32 = 16 MB, dead until gemm_corr
    gemm_nt128s<<<dim3(HDIM / 128, (BATCH * NTOK) / 128, 2), 256, 0, stream>>>(
        x, FDIM, W0, FDIM, Hpart, HDIM, BATCH * NTOK, FDIM / 2);
    combine_relu<<<dim3((BATCH * NTOK * HDIM / 4) / 256), 256, 0, stream>>>(
        Hpart, Hpart + (size_t)BATCH * NTOK * HDIM, b0, h);
    // Layer 1: e = h @ W1^T + b1
    gemm_nt64<<<dim3(EDIM / 64, (BATCH * NTOK) / 64), 256, 0, stream>>>(
        h, HDIM, W1, HDIM, b1, e, EDIM, HDIM);
    rownorm_kernel<<<dim3((BATCH * NTOK) / 4), 256, 0, stream>>>(e, dvec);
    // D from correlation (overwrites Hpart region)
    gemm_corr<<<dim3(NTOK / 128, NTOK / 128, BATCH), 256, 0, stream>>>(e, Dm, dvec);
    sat_row_kernel<<<dim3(NTOK, BATCH), 256, 0, stream>>>(Dm, Sp);
    satc1<<<dim3((NP1 + 255) / 256, 8, BATCH), 256, 0, stream>>>(Sp, aux);
    satc2<<<dim3((NP1 + 255) / 256, BATCH), 256, 0, stream>>>(aux);
    satc3<<<dim3((NP1 + 255) / 256, 8, BATCH), 256, 0, stream>>>(Sp, aux);
    diag_kernel<<<dim3((NP1 + 255) / 256, BATCH), 256, 0, stream>>>(Sp, dg);
    bsum_kernel<<<dim3(NTOK, BATCH), 256, 0, stream>>>(Sp, dg, Dm, CA);

    // Fused DP (cooperative launch for co-residency; fence-free sync).
    void* args[] = { (void*)&Dm, (void*)&CA, (void*)&CB, (void*)&tsum, (void*)&flags };
    hipError_t err = hipLaunchCooperativeKernel((const void*)dp_fused_kernel,
                                                dim3(DP_BX, BATCH), dim3(256),
                                                args, 0, stream);
    if (err != hipSuccess) {
        float* cp = CA; float* cn = CB;
        for (int kk = 1; kk < KSEG; ++kk) {
            dp_step_kernel<<<dim3(128, BATCH), 256, 0, stream>>>(Dm, cp, cn, tsum, kk);
            float* tmp = cp; cp = cn; cn = tmp;
        }
    }
    finalize_kernel<<<dim3(NTOK / 256, BATCH), 256, 0, stream>>>(tsum, out);
}